// Round 2
// baseline (2265.712 us; speedup 1.0000x reference)
//
#include <hip/hip_runtime.h>
#include <math.h>

#define BATCH 64
#define NTOK  729
#define DIM   64
#define NROWS 46656   // BATCH*NTOK

// ---------------------------------------------------------------------------
// Direct 3x3 SAME conv, NCHW, 27x27 spatial. v2:
//  - weights read directly from global with wave-uniform index -> SGPR s_loads
//  - staged input row stride 33 (bank-conflict-free-ish: py + 3*px mod 32)
//  - TC=4 couts/block -> 2x grid (4 blocks/CU)
//  - optional fused bias + BN-stats accumulation (nslab==1 convs)
// Input-side BN+ReLU fused via scsh = [scale[Cin] | shift[Cin]].
// Block: 256 threads; 243 active = 27 rows x 9 x-triples.
// ---------------------------------------------------------------------------
#define SROW 33
#define SCH  (29 * SROW)   // 957 floats per staged channel

template<int CIN_CHUNK, int TC, bool BN_IN, bool FUSE_STATS>
__global__ __launch_bounds__(256) void conv3x3_v2(
    const float* __restrict__ in, const float* __restrict__ wgt,
    const float* __restrict__ scsh, const float* __restrict__ bias,
    float* __restrict__ outp, double* __restrict__ stats,
    int Cin, int Cout, int cinPerSlab, int nslab)
{
  int groups = Cout / TC;
  int blocksPerB = groups * nslab;
  int b = blockIdx.x / blocksPerB;
  int rr = blockIdx.x % blocksPerB;
  int g = rr / nslab;
  int slab = rr % nslab;
  int c_begin = slab * cinPerSlab;
  int c_end = c_begin + cinPerSlab; if (c_end > Cin) c_end = Cin;

  __shared__ float s_in[CIN_CHUNK * SCH];
  __shared__ float s_sc[CIN_CHUNK];
  __shared__ float s_sh[CIN_CHUNK];
  __shared__ float s_red[4][TC][2];

  const int tid = threadIdx.x;
  const bool active = tid < 243;
  const int py = tid / 9;
  const int px3 = (tid % 9) * 3;

  float acc[TC][3];
  #pragma unroll
  for (int t = 0; t < TC; ++t) { acc[t][0]=0.f; acc[t][1]=0.f; acc[t][2]=0.f; }

  const size_t inB = (size_t)b * Cin;

  for (int c0 = c_begin; c0 < c_end; c0 += CIN_CHUNK) {
    int ccn = c_end - c0; if (ccn > CIN_CHUNK) ccn = CIN_CHUNK;
    if (BN_IN && tid < ccn) {
      s_sc[tid] = scsh[c0 + tid];
      s_sh[tid] = scsh[Cin + c0 + tid];
    }
    __syncthreads();   // protects s_in from previous iteration's readers
    for (int i = tid; i < ccn * SCH; i += 256) {
      int cc = i / SCH; int r2 = i - cc * SCH; int y = r2 / SROW; int x2 = r2 - y * SROW;
      float v = 0.f;
      if (y >= 1 && y <= 27 && x2 >= 1 && x2 <= 27) {
        v = in[(inB + (c0 + cc)) * 729 + (y - 1) * 27 + (x2 - 1)];
        if (BN_IN) v = fmaxf(fmaf(v, s_sc[cc], s_sh[cc]), 0.f);
      }
      s_in[i] = v;
    }
    __syncthreads();
    if (active) {
      const float* wbase = &wgt[((size_t)(g * TC) * Cin + c0) * 9];
      if (ccn == CIN_CHUNK) {
        #pragma unroll
        for (int cc = 0; cc < CIN_CHUNK; ++cc) {
          const float* bp = &s_in[cc * SCH + py * SROW + px3];
          float v00=bp[0],        v01=bp[1],        v02=bp[2],        v03=bp[3],        v04=bp[4];
          float v10=bp[SROW],     v11=bp[SROW+1],   v12=bp[SROW+2],   v13=bp[SROW+3],   v14=bp[SROW+4];
          float v20=bp[2*SROW],   v21=bp[2*SROW+1], v22=bp[2*SROW+2], v23=bp[2*SROW+3], v24=bp[2*SROW+4];
          #pragma unroll
          for (int t = 0; t < TC; ++t) {
            const float* wp = wbase + ((size_t)t * Cin + cc) * 9;  // uniform -> s_load
            float w0=wp[0],w1=wp[1],w2=wp[2],w3=wp[3],w4=wp[4],w5=wp[5],w6=wp[6],w7=wp[7],w8=wp[8];
            acc[t][0] += w0*v00+w1*v01+w2*v02 + w3*v10+w4*v11+w5*v12 + w6*v20+w7*v21+w8*v22;
            acc[t][1] += w0*v01+w1*v02+w2*v03 + w3*v11+w4*v12+w5*v13 + w6*v21+w7*v22+w8*v23;
            acc[t][2] += w0*v02+w1*v03+w2*v04 + w3*v12+w4*v13+w5*v14 + w6*v22+w7*v23+w8*v24;
          }
        }
      } else {
        for (int cc = 0; cc < ccn; ++cc) {
          const float* bp = &s_in[cc * SCH + py * SROW + px3];
          float v00=bp[0],        v01=bp[1],        v02=bp[2],        v03=bp[3],        v04=bp[4];
          float v10=bp[SROW],     v11=bp[SROW+1],   v12=bp[SROW+2],   v13=bp[SROW+3],   v14=bp[SROW+4];
          float v20=bp[2*SROW],   v21=bp[2*SROW+1], v22=bp[2*SROW+2], v23=bp[2*SROW+3], v24=bp[2*SROW+4];
          #pragma unroll
          for (int t = 0; t < TC; ++t) {
            const float* wp = wbase + ((size_t)t * Cin + cc) * 9;
            float w0=wp[0],w1=wp[1],w2=wp[2],w3=wp[3],w4=wp[4],w5=wp[5],w6=wp[6],w7=wp[7],w8=wp[8];
            acc[t][0] += w0*v00+w1*v01+w2*v02 + w3*v10+w4*v11+w5*v12 + w6*v20+w7*v21+w8*v22;
            acc[t][1] += w0*v01+w1*v02+w2*v03 + w3*v11+w4*v12+w5*v13 + w6*v21+w7*v22+w8*v23;
            acc[t][2] += w0*v02+w1*v03+w2*v04 + w3*v12+w4*v13+w5*v14 + w6*v22+w7*v23+w8*v24;
          }
        }
      }
    }
  }

  if (!FUSE_STATS) {
    if (active) {
      #pragma unroll
      for (int t = 0; t < TC; ++t) {
        size_t base = (((size_t)slab * BATCH + b) * Cout + (g * TC + t)) * 729 + py * 27 + px3;
        outp[base+0]=acc[t][0]; outp[base+1]=acc[t][1]; outp[base+2]=acc[t][2];
      }
    }
  } else {
    float sv[TC], sq[TC];
    #pragma unroll
    for (int t = 0; t < TC; ++t) { sv[t] = 0.f; sq[t] = 0.f; }
    if (active) {
      #pragma unroll
      for (int t = 0; t < TC; ++t) {
        float bv = bias[g * TC + t];
        float v0 = acc[t][0] + bv, v1 = acc[t][1] + bv, v2 = acc[t][2] + bv;
        size_t base = ((size_t)b * Cout + (g * TC + t)) * 729 + py * 27 + px3;
        outp[base+0]=v0; outp[base+1]=v1; outp[base+2]=v2;
        sv[t] = v0 + v1 + v2;
        sq[t] = v0*v0 + v1*v1 + v2*v2;
      }
    }
    #pragma unroll
    for (int off = 32; off > 0; off >>= 1) {
      #pragma unroll
      for (int t = 0; t < TC; ++t) {
        sv[t] += __shfl_down(sv[t], off);
        sq[t] += __shfl_down(sq[t], off);
      }
    }
    int wid = tid >> 6;
    __syncthreads();   // s_red reuse safety (also after compute)
    if ((tid & 63) == 0) {
      #pragma unroll
      for (int t = 0; t < TC; ++t) { s_red[wid][t][0] = sv[t]; s_red[wid][t][1] = sq[t]; }
    }
    __syncthreads();
    if (tid < TC) {
      float s1 = s_red[0][tid][0] + s_red[1][tid][0] + s_red[2][tid][0] + s_red[3][tid][0];
      float q1 = s_red[0][tid][1] + s_red[1][tid][1] + s_red[2][tid][1] + s_red[3][tid][1];
      atomicAdd(&stats[g * TC + tid], (double)s1);
      atomicAdd(&stats[Cout + g * TC + tid], (double)q1);
    }
  }
}

// ---------------------------------------------------------------------------
// Sum conv partials + bias -> out; accumulate per-channel sum/sumsq (BN stats)
// via double atomics. Block per (b, c). (conv1 only now)
// ---------------------------------------------------------------------------
__global__ __launch_bounds__(256) void conv_reduce_stats(
    const float* __restrict__ part, const float* __restrict__ bias,
    float* __restrict__ outp, double* __restrict__ stats, int C, int nslab)
{
  int b = blockIdx.x / C;
  int c = blockIdx.x % C;
  size_t slabStride = (size_t)BATCH * C * 729;
  size_t base = ((size_t)b * C + c) * 729;
  float bv = bias[c];
  float bsum = 0.f, bsq = 0.f;
  for (int e = threadIdx.x; e < 729; e += 256) {
    float v = bv;
    for (int s = 0; s < nslab; ++s) v += part[s*slabStride + base + e];
    outp[base + e] = v;
    bsum += v; bsq += v*v;
  }
  #pragma unroll
  for (int off = 32; off > 0; off >>= 1) {
    bsum += __shfl_down(bsum, off);
    bsq  += __shfl_down(bsq, off);
  }
  __shared__ float rs[4], rq[4];
  int wid = threadIdx.x >> 6;
  if ((threadIdx.x & 63) == 0) { rs[wid] = bsum; rq[wid] = bsq; }
  __syncthreads();
  if (threadIdx.x == 0) {
    float s1 = rs[0]+rs[1]+rs[2]+rs[3];
    float q1 = rq[0]+rq[1]+rq[2]+rq[3];
    atomicAdd(&stats[c], (double)s1);
    atomicAdd(&stats[C + c], (double)q1);
  }
}

// (sum, sumsq) + gamma/beta -> (scale, shift)
__global__ void bn_finalize(const double* __restrict__ stats,
                            const float* __restrict__ gamma, const float* __restrict__ beta,
                            float* __restrict__ scsh, int C, float invCount)
{
  int c = threadIdx.x + blockIdx.x * blockDim.x; if (c >= C) return;
  double mu = stats[c] * (double)invCount;
  double var = stats[C + c] * (double)invCount - mu * mu;
  float rstd = (float)(1.0 / sqrt(var + 1e-5));
  float sc = gamma[c] * rstd;
  scsh[c] = sc;
  scsh[C + c] = beta[c] - (float)mu * sc;
}

// ---------------------------------------------------------------------------
// BN+ReLU conv3 output and transpose [B,64,729] -> t [B,729,64]; also xx[b,n].
// ---------------------------------------------------------------------------
__global__ __launch_bounds__(256) void bn_transpose_xx(
    const float* __restrict__ c3, const float* __restrict__ scsh,
    float* __restrict__ t, float* __restrict__ xx)
{
  int b = blockIdx.x / 12, nt = blockIdx.x % 12, n0 = nt * 64;
  __shared__ float s[64 * 65];
  for (int i = threadIdx.x; i < 4096; i += 256) {
    int d = i >> 6, j = i & 63; int n = n0 + j;
    float v = 0.f;
    if (n < 729) {
      v = c3[((size_t)b * 64 + d) * 729 + n];
      v = fmaxf(fmaf(v, scsh[d], scsh[64 + d]), 0.f);
    }
    s[d * 65 + j] = v;
  }
  __syncthreads();
  for (int i = threadIdx.x; i < 4096; i += 256) {
    int j = i >> 6, d = i & 63; int n = n0 + j;
    if (n < 729) t[((size_t)b * 729 + n) * 64 + d] = s[d * 65 + j];
  }
  if (threadIdx.x < 64) {
    int j = threadIdx.x; int n = n0 + j;
    if (n < 729) {
      float sm = 0.f;
      #pragma unroll
      for (int d = 0; d < 64; ++d) { float v = s[d * 65 + j]; sm += v * v; }
      xx[b * 729 + n] = sm;
    }
  }
}

// ---------------------------------------------------------------------------
// hs = t @ w_self, hw = t @ w_nb.
// ---------------------------------------------------------------------------
__global__ __launch_bounds__(256) void gemm_selfnb(
    const float* __restrict__ t, const float* __restrict__ wself,
    const float* __restrict__ wnb, float* __restrict__ hs, float* __restrict__ hw)
{
  int b = blockIdx.x / 12, nt = blockIdx.x % 12, n0 = nt * 64;
  __shared__ float s_t[64 * 65], s_a[64 * 65], s_b[64 * 65];
  for (int i = threadIdx.x; i < 4096; i += 256) {
    int n = i >> 6, d = i & 63;
    s_t[n * 65 + d] = (n0 + n < 729) ? t[((size_t)b * 729 + n0 + n) * 64 + d] : 0.f;
    s_a[n * 65 + d] = wself[i];
    s_b[n * 65 + d] = wnb[i];
  }
  __syncthreads();
  int ty = threadIdx.x >> 4, tx = threadIdx.x & 15;
  float acc0[4][4], acc1[4][4];
  #pragma unroll
  for (int i = 0; i < 4; ++i)
    #pragma unroll
    for (int j = 0; j < 4; ++j) { acc0[i][j] = 0.f; acc1[i][j] = 0.f; }
  #pragma unroll 4
  for (int d = 0; d < 64; ++d) {
    float av[4], b1v[4], b2v[4];
    #pragma unroll
    for (int i = 0; i < 4; ++i) av[i] = s_t[(4*ty + i) * 65 + d];
    #pragma unroll
    for (int j = 0; j < 4; ++j) { b1v[j] = s_a[d * 65 + 4*tx + j]; b2v[j] = s_b[d * 65 + 4*tx + j]; }
    #pragma unroll
    for (int i = 0; i < 4; ++i)
      #pragma unroll
      for (int j = 0; j < 4; ++j) { acc0[i][j] += av[i]*b1v[j]; acc1[i][j] += av[i]*b2v[j]; }
  }
  #pragma unroll
  for (int i = 0; i < 4; ++i) {
    int n = n0 + 4*ty + i;
    if (n < 729) {
      #pragma unroll
      for (int j = 0; j < 4; ++j) {
        size_t o = ((size_t)b * 729 + n) * 64 + 4*tx + j;
        hs[o] = acc0[i][j];
        hw[o] = acc1[i][j];
      }
    }
  }
}

// ---------------------------------------------------------------------------
// kNN: fused distance GEMM + streaming top-8 (ties: lexicographic (val,idx)).
// ---------------------------------------------------------------------------
__global__ __launch_bounds__(256) void dist_topk(
    const float* __restrict__ t, const float* __restrict__ xx, int* __restrict__ nbr)
{
  int b = blockIdx.x / 12, nt = blockIdx.x % 12, n0 = nt * 64;
  __shared__ float s_n[64 * 65];
  __shared__ float s_m[64 * 65];
  __shared__ float s_S[64 * 65];

  float kv[8]; int ki[8];
  #pragma unroll
  for (int i = 0; i < 8; ++i) { kv[i] = 3.0e38f; ki[i] = 0x7fffffff; }

  for (int i = threadIdx.x; i < 4096; i += 256) {
    int n = i >> 6, d = i & 63;
    s_n[n * 65 + d] = (n0 + n < 729) ? t[((size_t)b * 729 + n0 + n) * 64 + d] : 0.f;
  }
  int ty = threadIdx.x >> 4, tx = threadIdx.x & 15;
  int r = threadIdx.x & 63, q = threadIdx.x >> 6;
  int n_self = n0 + r;

  for (int mt = 0; mt < 12; ++mt) {
    int m0 = mt * 64;
    __syncthreads();
    for (int i = threadIdx.x; i < 4096; i += 256) {
      int m = i >> 6, d = i & 63;
      s_m[m * 65 + d] = (m0 + m < 729) ? t[((size_t)b * 729 + m0 + m) * 64 + d] : 0.f;
    }
    __syncthreads();
    float acc[4][4];
    #pragma unroll
    for (int i = 0; i < 4; ++i)
      #pragma unroll
      for (int j = 0; j < 4; ++j) acc[i][j] = 0.f;
    #pragma unroll 4
    for (int d = 0; d < 64; ++d) {
      float av[4], bv[4];
      #pragma unroll
      for (int i = 0; i < 4; ++i) av[i] = s_n[(4*ty + i) * 65 + d];
      #pragma unroll
      for (int j = 0; j < 4; ++j) bv[j] = s_m[(4*tx + j) * 65 + d];
      #pragma unroll
      for (int i = 0; i < 4; ++i)
        #pragma unroll
        for (int j = 0; j < 4; ++j) acc[i][j] += av[i] * bv[j];
    }
    #pragma unroll
    for (int j = 0; j < 4; ++j) {
      int m = m0 + 4*tx + j;
      float xm = (m < 729) ? xx[b * 729 + m] : 3.0e38f;
      #pragma unroll
      for (int i = 0; i < 4; ++i)
        s_S[(4*ty + i) * 65 + 4*tx + j] = fmaf(-2.f, acc[i][j], xm);
    }
    __syncthreads();
    for (int i2 = 0; i2 < 16; ++i2) {
      int m = m0 + q * 16 + i2;
      float sv = s_S[r * 65 + q * 16 + i2];
      bool valid = (m < 729) && (m != n_self);
      bool lt = valid && ((sv < kv[7]) || (sv == kv[7] && m < ki[7]));
      if (lt) {
        float cv = sv; int ci = m;
        #pragma unroll
        for (int ii = 0; ii < 8; ++ii) {
          bool less = (cv < kv[ii]) || (cv == kv[ii] && ci < ki[ii]);
          float tv = less ? kv[ii] : cv; int ti = less ? ki[ii] : ci;
          kv[ii] = less ? cv : kv[ii]; ki[ii] = less ? ci : ki[ii];
          cv = tv; ci = ti;
        }
      }
    }
  }
  __syncthreads();
  float* mv = s_m;
  int*   mi = (int*)s_n;
  #pragma unroll
  for (int i2 = 0; i2 < 8; ++i2) { mv[r*33 + q*8 + i2] = kv[i2]; mi[r*33 + q*8 + i2] = ki[i2]; }
  __syncthreads();
  if (threadIdx.x < 64) {
    int n = n0 + threadIdx.x;
    if (n < 729) {
      int rb = threadIdx.x * 33;
      int p0 = 0, p1 = 0, p2 = 0, p3 = 0;
      int* op = &nbr[((size_t)b * 729 + n) * 8];
      for (int o = 0; o < 8; ++o) {
        float bvv = 3.5e38f; int bii = 0x7fffffff; int bq = 0;
        {
          float v = mv[rb + 0*8 + p0]; int ii = mi[rb + 0*8 + p0];
          if (v < bvv || (v == bvv && ii < bii)) { bvv = v; bii = ii; bq = 0; }
        }
        {
          float v = mv[rb + 1*8 + p1]; int ii = mi[rb + 1*8 + p1];
          if (v < bvv || (v == bvv && ii < bii)) { bvv = v; bii = ii; bq = 1; }
        }
        {
          float v = mv[rb + 2*8 + p2]; int ii = mi[rb + 2*8 + p2];
          if (v < bvv || (v == bvv && ii < bii)) { bvv = v; bii = ii; bq = 2; }
        }
        {
          float v = mv[rb + 3*8 + p3]; int ii = mi[rb + 3*8 + p3];
          if (v < bvv || (v == bvv && ii < bii)) { bvv = v; bii = ii; bq = 3; }
        }
        p0 += (bq == 0); p1 += (bq == 1); p2 += (bq == 2); p3 += (bq == 3);
        op[o] = bii;
      }
    }
  }
}

// ---------------------------------------------------------------------------
__global__ __launch_bounds__(256) void gkan_kernel(
    const float* __restrict__ hs, const float* __restrict__ hw,
    const int* __restrict__ nbr, const float* __restrict__ bias,
    const float* __restrict__ kan_a, const float* __restrict__ kan_b,
    float* __restrict__ gpre)
{
  int row = blockIdx.x * 4 + (threadIdx.x >> 6);
  int d = threadIdx.x & 63;
  float degf = 8.0f + 1e-6f;
  float coef = 1.0f / degf;
  size_t bbase = (size_t)(row / 729) * 729;
  float v = hs[(size_t)row * 64 + d] + hw[(size_t)row * 64 + d] + bias[d];
  float nsum = 0.f;
  #pragma unroll
  for (int j = 0; j < 8; ++j) {
    int m = nbr[(size_t)row * 8 + j];
    nsum += hw[(bbase + m) * 64 + d];
  }
  v += coef * nsum;
  float a0 = kan_a[d*3], a1 = kan_a[d*3+1], a2 = kan_a[d*3+2];
  float b0 = kan_b[d*2], b1 = kan_b[d*2+1];
  float v2 = v * v;
  float num = a0 + a1*v + a2*v2;
  float den = 1.f + fabsf(b0*v + b1*v2);
  gpre[(size_t)row * 64 + d] = num / (den + 1e-8f);
}

__global__ __launch_bounds__(256) void stats_tok(
    const float* __restrict__ g, double* __restrict__ stats)
{
  int d = threadIdx.x & 63, qq = threadIdx.x >> 6;
  int r0 = blockIdx.x * 183;
  int rend = r0 + 183; if (rend > NROWS) rend = NROWS;
  float sm = 0.f, sq = 0.f;
  for (int r = r0 + qq; r < rend; r += 4) {
    float v = g[(size_t)r * 64 + d];
    sm += v; sq += v * v;
  }
  __shared__ float ls[256], lq[256];
  ls[threadIdx.x] = sm; lq[threadIdx.x] = sq;
  __syncthreads();
  if (threadIdx.x < 64) {
    sm = ls[d] + ls[64+d] + ls[128+d] + ls[192+d];
    sq = lq[d] + lq[64+d] + lq[128+d] + lq[192+d];
    atomicAdd(&stats[d], (double)sm);
    atomicAdd(&stats[64 + d], (double)sq);
  }
}

// ---------------------------------------------------------------------------
__global__ __launch_bounds__(256) void fuzzy_attn(
    const float* __restrict__ gpre, const float* __restrict__ scshG,
    const float* __restrict__ centers, const float* __restrict__ gam,
    const float* __restrict__ w1, const float* __restrict__ b1,
    const float* __restrict__ w2, const float* __restrict__ b2,
    float* __restrict__ g2)
{
  int wv = threadIdx.x >> 6, d = threadIdx.x & 63;
  int row = blockIdx.x * 4 + wv;
  __shared__ float s_rbf[4][64];
  __shared__ float s_a1[4][16];
  float v = gpre[(size_t)row * 64 + d];
  float gn = fmaf(v, scshG[d], scshG[64 + d]);
  float acc = 0.f;
  #pragma unroll
  for (int f = 0; f < 9; ++f) {
    float dc = gn - centers[d*9 + f];
    acc += expf(-fabsf(gam[d*9 + f]) * dc * dc);
  }
  s_rbf[wv][d] = acc + 9e-10f;
  __syncthreads();
  if (d < 16) {
    float a = b1[d];
    #pragma unroll 8
    for (int k = 0; k < 64; ++k) a += w1[d*64 + k] * s_rbf[wv][k];
    s_a1[wv][d] = fmaxf(a, 0.f);
  }
  __syncthreads();
  float a2 = b2[d];
  #pragma unroll
  for (int i = 0; i < 16; ++i) a2 += w2[d*16 + i] * s_a1[wv][i];
  float sig = 1.f / (1.f + expf(-a2));
  g2[(size_t)row * 64 + d] = gn * (1.f + sig);
}

__global__ __launch_bounds__(256) void pool_kernel(
    const float* __restrict__ g2, const float* __restrict__ scshF, float* __restrict__ p)
{
  int b = blockIdx.x;
  int d = threadIdx.x & 63, qq = threadIdx.x >> 6;
  float sc = scshF[d], sh = scshF[64 + d];
  float sm = 0.f, mx = -3.0e38f;
  for (int n = qq; n < 729; n += 4) {
    float v = fmaf(g2[((size_t)b * 729 + n) * 64 + d], sc, sh);
    sm += v; mx = fmaxf(mx, v);
  }
  __shared__ float ls[256], lm[256];
  ls[threadIdx.x] = sm; lm[threadIdx.x] = mx;
  __syncthreads();
  if (threadIdx.x < 64) {
    sm = ls[d] + ls[64+d] + ls[128+d] + ls[192+d];
    mx = fmaxf(fmaxf(lm[d], lm[64+d]), fmaxf(lm[128+d], lm[192+d]));
    p[b * 64 + d] = 0.5f * (sm / 729.f) + 0.5f * mx;
  }
}

__global__ __launch_bounds__(256) void classifier(
    const float* __restrict__ p, const float* __restrict__ f1w, const float* __restrict__ f1b,
    const float* __restrict__ bng, const float* __restrict__ bnb,
    const float* __restrict__ f2w, const float* __restrict__ f2b, float* __restrict__ outp)
{
  __shared__ float s_p[64 * 64];
  __shared__ float s_c[64 * 128];
  __shared__ float s_sc[128], s_sh[128];
  for (int i = threadIdx.x; i < 4096; i += 256) s_p[i] = p[i];
  __syncthreads();
  for (int o = threadIdx.x; o < 8192; o += 256) {
    int b = o >> 7, h = o & 127;
    float acc = f1b[h];
    #pragma unroll 8
    for (int d = 0; d < 64; ++d) acc += s_p[b*64 + d] * f1w[h*64 + d];
    s_c[o] = acc;
  }
  __syncthreads();
  if (threadIdx.x < 128) {
    int h = threadIdx.x;
    float sm = 0.f, sq = 0.f;
    for (int b = 0; b < 64; ++b) { float v = s_c[b*128 + h]; sm += v; sq += v*v; }
    float mu = sm / 64.f;
    float var = sq / 64.f - mu * mu;
    float rstd = rsqrtf(var + 1e-5f);
    float sc = bng[h] * rstd;
    s_sc[h] = sc; s_sh[h] = bnb[h] - mu * sc;
  }
  __syncthreads();
  for (int o = threadIdx.x; o < 1024; o += 256) {
    int b = o >> 4, j = o & 15;
    float acc = f2b[j];
    #pragma unroll 8
    for (int h = 0; h < 128; ++h) {
      float v = fmaxf(fmaf(s_c[b*128 + h], s_sc[h], s_sh[h]), 0.f);
      acc += f2w[j*128 + h] * v;
    }
    outp[o] = acc;
  }
}

// ---------------------------------------------------------------------------
extern "C" void kernel_launch(void* const* d_in, const int* in_sizes, int n_in,
                              void* d_out, int out_size, void* d_ws, size_t ws_size,
                              hipStream_t stream)
{
  const float* x      = (const float*)d_in[0];
  const float* c1w    = (const float*)d_in[1];
  const float* c1b    = (const float*)d_in[2];
  const float* bn1g   = (const float*)d_in[3];
  const float* bn1b   = (const float*)d_in[4];
  const float* c2wt   = (const float*)d_in[5];
  const float* c2b    = (const float*)d_in[6];
  const float* bn2g   = (const float*)d_in[7];
  const float* bn2b   = (const float*)d_in[8];
  const float* c3wt   = (const float*)d_in[9];
  const float* c3b    = (const float*)d_in[10];
  const float* bn3g   = (const float*)d_in[11];
  const float* bn3b   = (const float*)d_in[12];
  const float* wself  = (const float*)d_in[13];
  const float* wnb    = (const float*)d_in[14];
  const float* gbias  = (const float*)d_in[15];
  const float* kana   = (const float*)d_in[16];
  const float* kanb   = (const float*)d_in[17];
  const float* gbng   = (const float*)d_in[18];
  const float* gbnb   = (const float*)d_in[19];
  const float* cent   = (const float*)d_in[20];
  const float* gamr   = (const float*)d_in[21];
  const float* aw1    = (const float*)d_in[22];
  const float* ab1    = (const float*)d_in[23];
  const float* aw2    = (const float*)d_in[24];
  const float* ab2    = (const float*)d_in[25];
  const float* fbng   = (const float*)d_in[26];
  const float* fbnb   = (const float*)d_in[27];
  const float* f1w    = (const float*)d_in[28];
  const float* f1b    = (const float*)d_in[29];
  const float* cbng   = (const float*)d_in[30];
  const float* cbnb   = (const float*)d_in[31];
  const float* f2w    = (const float*)d_in[32];
  const float* f2b    = (const float*)d_in[33];

  char* ws = (char*)d_ws;
  float*  P     = (float*) (ws + 0);          // 11,943,936 B: conv1 partials (2 slabs)
  float*  c1    = (float*) (ws + 11943936);   //  5,971,968 B
  float*  c2    = (float*) (ws + 17915904);   // 11,943,936 B
  float*  c3    = (float*) (ws + 29859840);   // 11,943,936 B
  float*  t     = (float*) (ws + 41803776);   // 11,943,936 B
  int*    nbr   = (int*)   (ws + 53747712);   //  1,492,992 B
  float*  xx    = (float*) (ws + 55240704);   //    186,624 B
  double* stats = (double*)(ws + 55427328);   //      4,608 B (576 doubles)
  float*  scsh  = (float*) (ws + 55431936);   //      2,304 B (576 floats)
  float*  pbuf  = (float*) (ws + 55434240);   //     16,384 B
  float* hs   = c2;
  float* hw   = P;
  float* gpre = c3;
  float* g2   = t;

  hipMemsetAsync(stats, 0, 576 * sizeof(double), stream);

  const float inv = 1.0f / 46656.0f;

  // conv1: TC=4, 8 groups x 2 slabs -> 1024 blocks; partial P, separate reduce
  conv3x3_v2<8,4,false,false><<<dim3(1024), dim3(256), 0, stream>>>(
      x,  c1w, nullptr, nullptr, P, nullptr, 200, 32, 100, 2);
  conv_reduce_stats<<<dim3(2048), dim3(256), 0, stream>>>(P, c1b, c1, stats, 32, 2);
  bn_finalize<<<dim3(1), dim3(32), 0, stream>>>(stats, bn1g, bn1b, scsh, 32, inv);
  // conv2: fused bias+stats, BN(conv1) on input
  conv3x3_v2<8,4,true,true><<<dim3(1024), dim3(256), 0, stream>>>(
      c1, c2wt, scsh, c2b, c2, stats + 64, 32, 64, 32, 1);
  bn_finalize<<<dim3(1), dim3(64), 0, stream>>>(stats + 64, bn2g, bn2b, scsh + 64, 64, inv);
  // conv3: fused bias+stats, BN(conv2) on input
  conv3x3_v2<8,4,true,true><<<dim3(1024), dim3(256), 0, stream>>>(
      c2, c3wt, scsh + 64, c3b, c3, stats + 192, 64, 64, 64, 1);
  bn_finalize<<<dim3(1), dim3(64), 0, stream>>>(stats + 192, bn3g, bn3b, scsh + 192, 64, inv);
  // tokens
  bn_transpose_xx<<<dim3(768), dim3(256), 0, stream>>>(c3, scsh + 192, t, xx);
  gemm_selfnb<<<dim3(768), dim3(256), 0, stream>>>(t, wself, wnb, hs, hw);
  dist_topk<<<dim3(768), dim3(256), 0, stream>>>(t, xx, nbr);
  gkan_kernel<<<dim3(11664), dim3(256), 0, stream>>>(hs, hw, nbr, gbias, kana, kanb, gpre);
  stats_tok<<<dim3(256), dim3(256), 0, stream>>>(gpre, stats + 320);
  bn_finalize<<<dim3(1), dim3(64), 0, stream>>>(stats + 320, gbng, gbnb, scsh + 320, 64, inv);
  fuzzy_attn<<<dim3(11664), dim3(256), 0, stream>>>(gpre, scsh + 320, cent, gamr, aw1, ab1, aw2, ab2, g2);
  stats_tok<<<dim3(256), dim3(256), 0, stream>>>(g2, stats + 448);
  bn_finalize<<<dim3(1), dim3(64), 0, stream>>>(stats + 448, fbng, fbnb, scsh + 448, 64, inv);
  pool_kernel<<<dim3(64), dim3(256), 0, stream>>>(g2, scsh + 448, pbuf);
  classifier<<<dim3(1), dim3(256), 0, stream>>>(pbuf, f1w, f1b, cbng, cbnb, f2w, f2b, (float*)d_out);
}

// Round 3
// 1065.546 us; speedup vs baseline: 2.1263x; 2.1263x over previous
//
#include <hip/hip_runtime.h>
#include <math.h>

#define BATCH 64
#define NTOK  729
#define DIM   64
#define NROWS 46656   // BATCH*NTOK

// ---------------------------------------------------------------------------
// Direct 3x3 SAME conv, NCHW, 27x27 spatial. v3 (= R1 structure + fixes):
//  - weights staged in LDS (NOT global: R2 showed global-in-loop = 2x regress)
//  - staged input row stride 33: bank = py+3px+j mod 32, mult <= 3 (~free)
//  - weight stride padded to 12 floats -> 2x ds_read_b128 + 1x b32 per (t,cc)
//  - grid 1024 via Cin slabs (4 blocks/CU; R1's 512 = 2/CU capped occupancy)
// Input-side BN+ReLU fused via scsh = [scale[Cin] | shift[Cin]].
// Block: 256 threads; 243 active = 27 rows x 9 x-triples, 3 px/thread.
// Output: partial buffer [slab][B][Cout][729].
// ---------------------------------------------------------------------------
#define SROW 33
#define SCH  (29 * SROW)   // 957 floats per staged channel

template<int CIN_CHUNK, int TC, bool BN_IN>
__global__ __launch_bounds__(256) void conv3x3_v3(
    const float* __restrict__ in, const float* __restrict__ wgt,
    const float* __restrict__ scsh, float* __restrict__ outp,
    int Cin, int Cout, int cinPerSlab, int nslab)
{
  int groups = Cout / TC;
  int blocksPerB = groups * nslab;
  int b = blockIdx.x / blocksPerB;
  int rr = blockIdx.x % blocksPerB;
  int g = rr / nslab;
  int slab = rr % nslab;
  int c_begin = slab * cinPerSlab;
  int c_end = c_begin + cinPerSlab; if (c_end > Cin) c_end = Cin;

  __shared__ float s_in[CIN_CHUNK * SCH];
  __shared__ float s_w[TC * CIN_CHUNK * 12];   // stride 12 -> 16B aligned
  __shared__ float s_sc[CIN_CHUNK];
  __shared__ float s_sh[CIN_CHUNK];

  const int tid = threadIdx.x;
  const bool active = tid < 243;
  const int py = tid / 9;
  const int px3 = (tid % 9) * 3;

  float acc[TC][3];
  #pragma unroll
  for (int t = 0; t < TC; ++t) { acc[t][0]=0.f; acc[t][1]=0.f; acc[t][2]=0.f; }

  const size_t inB = (size_t)b * Cin;

  for (int c0 = c_begin; c0 < c_end; c0 += CIN_CHUNK) {
    int ccn = c_end - c0; if (ccn > CIN_CHUNK) ccn = CIN_CHUNK;
    if (BN_IN && tid < ccn) {
      s_sc[tid] = scsh[c0 + tid];
      s_sh[tid] = scsh[Cin + c0 + tid];
    }
    __syncthreads();   // protects s_in/s_w from previous iteration's readers
    // stage input chunk (zero-padded 29x29 -> stride-33 rows)
    for (int i = tid; i < CIN_CHUNK * SCH; i += 256) {
      int cc = i / SCH; int r2 = i - cc * SCH; int y = r2 / SROW; int x2 = r2 - y * SROW;
      float v = 0.f;
      if (cc < ccn && y >= 1 && y <= 27 && x2 >= 1 && x2 <= 27) {
        v = in[(inB + (c0 + cc)) * 729 + (y - 1) * 27 + (x2 - 1)];
        if (BN_IN) v = fmaxf(fmaf(v, s_sc[cc], s_sh[cc]), 0.f);
      }
      s_in[i] = v;
    }
    // stage weights, padded stride 12
    for (int i = tid; i < TC * CIN_CHUNK * 9; i += 256) {
      int t = i / (CIN_CHUNK * 9); int r2 = i - t * CIN_CHUNK * 9;
      int cc = r2 / 9; int k = r2 - cc * 9;
      float wv = 0.f;
      if (cc < ccn) wv = wgt[((size_t)(g * TC + t) * Cin + (c0 + cc)) * 9 + k];
      s_w[(t * CIN_CHUNK + cc) * 12 + k] = wv;
    }
    __syncthreads();
    if (active) {
      #pragma unroll 1
      for (int cc = 0; cc < ccn; ++cc) {
        const float* bp = &s_in[cc * SCH + py * SROW + px3];
        float v00=bp[0],        v01=bp[1],        v02=bp[2],        v03=bp[3],        v04=bp[4];
        float v10=bp[SROW],     v11=bp[SROW+1],   v12=bp[SROW+2],   v13=bp[SROW+3],   v14=bp[SROW+4];
        float v20=bp[2*SROW],   v21=bp[2*SROW+1], v22=bp[2*SROW+2], v23=bp[2*SROW+3], v24=bp[2*SROW+4];
        #pragma unroll
        for (int t = 0; t < TC; ++t) {
          const float4 wa = *(const float4*)&s_w[(t * CIN_CHUNK + cc) * 12];
          const float4 wb = *(const float4*)&s_w[(t * CIN_CHUNK + cc) * 12 + 4];
          const float  w8 = s_w[(t * CIN_CHUNK + cc) * 12 + 8];
          acc[t][0] += wa.x*v00+wa.y*v01+wa.z*v02 + wa.w*v10+wb.x*v11+wb.y*v12 + wb.z*v20+wb.w*v21+w8*v22;
          acc[t][1] += wa.x*v01+wa.y*v02+wa.z*v03 + wa.w*v11+wb.x*v12+wb.y*v13 + wb.z*v21+wb.w*v22+w8*v23;
          acc[t][2] += wa.x*v02+wa.y*v03+wa.z*v04 + wa.w*v12+wb.x*v13+wb.y*v14 + wb.z*v22+wb.w*v23+w8*v24;
        }
      }
    }
  }
  if (active) {
    #pragma unroll
    for (int t = 0; t < TC; ++t) {
      size_t base = (((size_t)slab * BATCH + b) * Cout + (g * TC + t)) * 729 + py * 27 + px3;
      outp[base+0]=acc[t][0]; outp[base+1]=acc[t][1]; outp[base+2]=acc[t][2];
    }
  }
}

// ---------------------------------------------------------------------------
// Sum conv partials + bias -> out; accumulate per-channel sum/sumsq (BN stats)
// via double atomics. Block per (b, c).
// ---------------------------------------------------------------------------
__global__ __launch_bounds__(256) void conv_reduce_stats(
    const float* __restrict__ part, const float* __restrict__ bias,
    float* __restrict__ outp, double* __restrict__ stats, int C, int nslab)
{
  int b = blockIdx.x / C;
  int c = blockIdx.x % C;
  size_t slabStride = (size_t)BATCH * C * 729;
  size_t base = ((size_t)b * C + c) * 729;
  float bv = bias[c];
  float bsum = 0.f, bsq = 0.f;
  for (int e = threadIdx.x; e < 729; e += 256) {
    float v = bv;
    for (int s = 0; s < nslab; ++s) v += part[s*slabStride + base + e];
    outp[base + e] = v;
    bsum += v; bsq += v*v;
  }
  #pragma unroll
  for (int off = 32; off > 0; off >>= 1) {
    bsum += __shfl_down(bsum, off);
    bsq  += __shfl_down(bsq, off);
  }
  __shared__ float rs[4], rq[4];
  int wid = threadIdx.x >> 6;
  if ((threadIdx.x & 63) == 0) { rs[wid] = bsum; rq[wid] = bsq; }
  __syncthreads();
  if (threadIdx.x == 0) {
    float s1 = rs[0]+rs[1]+rs[2]+rs[3];
    float q1 = rq[0]+rq[1]+rq[2]+rq[3];
    atomicAdd(&stats[c], (double)s1);
    atomicAdd(&stats[C + c], (double)q1);
  }
}

// (sum, sumsq) + gamma/beta -> (scale, shift)
__global__ void bn_finalize(const double* __restrict__ stats,
                            const float* __restrict__ gamma, const float* __restrict__ beta,
                            float* __restrict__ scsh, int C, float invCount)
{
  int c = threadIdx.x + blockIdx.x * blockDim.x; if (c >= C) return;
  double mu = stats[c] * (double)invCount;
  double var = stats[C + c] * (double)invCount - mu * mu;
  float rstd = (float)(1.0 / sqrt(var + 1e-5));
  float sc = gamma[c] * rstd;
  scsh[c] = sc;
  scsh[C + c] = beta[c] - (float)mu * sc;
}

// ---------------------------------------------------------------------------
// BN+ReLU conv3 output and transpose [B,64,729] -> t [B,729,64]; also xx[b,n].
// ---------------------------------------------------------------------------
__global__ __launch_bounds__(256) void bn_transpose_xx(
    const float* __restrict__ c3, const float* __restrict__ scsh,
    float* __restrict__ t, float* __restrict__ xx)
{
  int b = blockIdx.x / 12, nt = blockIdx.x % 12, n0 = nt * 64;
  __shared__ float s[64 * 65];
  for (int i = threadIdx.x; i < 4096; i += 256) {
    int d = i >> 6, j = i & 63; int n = n0 + j;
    float v = 0.f;
    if (n < 729) {
      v = c3[((size_t)b * 64 + d) * 729 + n];
      v = fmaxf(fmaf(v, scsh[d], scsh[64 + d]), 0.f);
    }
    s[d * 65 + j] = v;
  }
  __syncthreads();
  for (int i = threadIdx.x; i < 4096; i += 256) {
    int j = i >> 6, d = i & 63; int n = n0 + j;
    if (n < 729) t[((size_t)b * 729 + n) * 64 + d] = s[d * 65 + j];
  }
  if (threadIdx.x < 64) {
    int j = threadIdx.x; int n = n0 + j;
    if (n < 729) {
      float sm = 0.f;
      #pragma unroll
      for (int d = 0; d < 64; ++d) { float v = s[d * 65 + j]; sm += v * v; }
      xx[b * 729 + n] = sm;
    }
  }
}

// ---------------------------------------------------------------------------
// hs = t @ w_self, hw = t @ w_nb.
// ---------------------------------------------------------------------------
__global__ __launch_bounds__(256) void gemm_selfnb(
    const float* __restrict__ t, const float* __restrict__ wself,
    const float* __restrict__ wnb, float* __restrict__ hs, float* __restrict__ hw)
{
  int b = blockIdx.x / 12, nt = blockIdx.x % 12, n0 = nt * 64;
  __shared__ float s_t[64 * 65], s_a[64 * 65], s_b[64 * 65];
  for (int i = threadIdx.x; i < 4096; i += 256) {
    int n = i >> 6, d = i & 63;
    s_t[n * 65 + d] = (n0 + n < 729) ? t[((size_t)b * 729 + n0 + n) * 64 + d] : 0.f;
    s_a[n * 65 + d] = wself[i];
    s_b[n * 65 + d] = wnb[i];
  }
  __syncthreads();
  int ty = threadIdx.x >> 4, tx = threadIdx.x & 15;
  float acc0[4][4], acc1[4][4];
  #pragma unroll
  for (int i = 0; i < 4; ++i)
    #pragma unroll
    for (int j = 0; j < 4; ++j) { acc0[i][j] = 0.f; acc1[i][j] = 0.f; }
  #pragma unroll 4
  for (int d = 0; d < 64; ++d) {
    float av[4], b1v[4], b2v[4];
    #pragma unroll
    for (int i = 0; i < 4; ++i) av[i] = s_t[(4*ty + i) * 65 + d];
    #pragma unroll
    for (int j = 0; j < 4; ++j) { b1v[j] = s_a[d * 65 + 4*tx + j]; b2v[j] = s_b[d * 65 + 4*tx + j]; }
    #pragma unroll
    for (int i = 0; i < 4; ++i)
      #pragma unroll
      for (int j = 0; j < 4; ++j) { acc0[i][j] += av[i]*b1v[j]; acc1[i][j] += av[i]*b2v[j]; }
  }
  #pragma unroll
  for (int i = 0; i < 4; ++i) {
    int n = n0 + 4*ty + i;
    if (n < 729) {
      #pragma unroll
      for (int j = 0; j < 4; ++j) {
        size_t o = ((size_t)b * 729 + n) * 64 + 4*tx + j;
        hs[o] = acc0[i][j];
        hw[o] = acc1[i][j];
      }
    }
  }
}

// ---------------------------------------------------------------------------
// kNN: fused distance GEMM + streaming top-8 (ties: lexicographic (val,idx)).
// ---------------------------------------------------------------------------
__global__ __launch_bounds__(256) void dist_topk(
    const float* __restrict__ t, const float* __restrict__ xx, int* __restrict__ nbr)
{
  int b = blockIdx.x / 12, nt = blockIdx.x % 12, n0 = nt * 64;
  __shared__ float s_n[64 * 65];
  __shared__ float s_m[64 * 65];
  __shared__ float s_S[64 * 65];

  float kv[8]; int ki[8];
  #pragma unroll
  for (int i = 0; i < 8; ++i) { kv[i] = 3.0e38f; ki[i] = 0x7fffffff; }

  for (int i = threadIdx.x; i < 4096; i += 256) {
    int n = i >> 6, d = i & 63;
    s_n[n * 65 + d] = (n0 + n < 729) ? t[((size_t)b * 729 + n0 + n) * 64 + d] : 0.f;
  }
  int ty = threadIdx.x >> 4, tx = threadIdx.x & 15;
  int r = threadIdx.x & 63, q = threadIdx.x >> 6;
  int n_self = n0 + r;

  for (int mt = 0; mt < 12; ++mt) {
    int m0 = mt * 64;
    __syncthreads();
    for (int i = threadIdx.x; i < 4096; i += 256) {
      int m = i >> 6, d = i & 63;
      s_m[m * 65 + d] = (m0 + m < 729) ? t[((size_t)b * 729 + m0 + m) * 64 + d] : 0.f;
    }
    __syncthreads();
    float acc[4][4];
    #pragma unroll
    for (int i = 0; i < 4; ++i)
      #pragma unroll
      for (int j = 0; j < 4; ++j) acc[i][j] = 0.f;
    #pragma unroll 4
    for (int d = 0; d < 64; ++d) {
      float av[4], bv[4];
      #pragma unroll
      for (int i = 0; i < 4; ++i) av[i] = s_n[(4*ty + i) * 65 + d];
      #pragma unroll
      for (int j = 0; j < 4; ++j) bv[j] = s_m[(4*tx + j) * 65 + d];
      #pragma unroll
      for (int i = 0; i < 4; ++i)
        #pragma unroll
        for (int j = 0; j < 4; ++j) acc[i][j] += av[i] * bv[j];
    }
    #pragma unroll
    for (int j = 0; j < 4; ++j) {
      int m = m0 + 4*tx + j;
      float xm = (m < 729) ? xx[b * 729 + m] : 3.0e38f;
      #pragma unroll
      for (int i = 0; i < 4; ++i)
        s_S[(4*ty + i) * 65 + 4*tx + j] = fmaf(-2.f, acc[i][j], xm);
    }
    __syncthreads();
    for (int i2 = 0; i2 < 16; ++i2) {
      int m = m0 + q * 16 + i2;
      float sv = s_S[r * 65 + q * 16 + i2];
      bool valid = (m < 729) && (m != n_self);
      bool lt = valid && ((sv < kv[7]) || (sv == kv[7] && m < ki[7]));
      if (lt) {
        float cv = sv; int ci = m;
        #pragma unroll
        for (int ii = 0; ii < 8; ++ii) {
          bool less = (cv < kv[ii]) || (cv == kv[ii] && ci < ki[ii]);
          float tv = less ? kv[ii] : cv; int ti = less ? ki[ii] : ci;
          kv[ii] = less ? cv : kv[ii]; ki[ii] = less ? ci : ki[ii];
          cv = tv; ci = ti;
        }
      }
    }
  }
  __syncthreads();
  float* mv = s_m;
  int*   mi = (int*)s_n;
  #pragma unroll
  for (int i2 = 0; i2 < 8; ++i2) { mv[r*33 + q*8 + i2] = kv[i2]; mi[r*33 + q*8 + i2] = ki[i2]; }
  __syncthreads();
  if (threadIdx.x < 64) {
    int n = n0 + threadIdx.x;
    if (n < 729) {
      int rb = threadIdx.x * 33;
      int p0 = 0, p1 = 0, p2 = 0, p3 = 0;
      int* op = &nbr[((size_t)b * 729 + n) * 8];
      for (int o = 0; o < 8; ++o) {
        float bvv = 3.5e38f; int bii = 0x7fffffff; int bq = 0;
        {
          float v = mv[rb + 0*8 + p0]; int ii = mi[rb + 0*8 + p0];
          if (v < bvv || (v == bvv && ii < bii)) { bvv = v; bii = ii; bq = 0; }
        }
        {
          float v = mv[rb + 1*8 + p1]; int ii = mi[rb + 1*8 + p1];
          if (v < bvv || (v == bvv && ii < bii)) { bvv = v; bii = ii; bq = 1; }
        }
        {
          float v = mv[rb + 2*8 + p2]; int ii = mi[rb + 2*8 + p2];
          if (v < bvv || (v == bvv && ii < bii)) { bvv = v; bii = ii; bq = 2; }
        }
        {
          float v = mv[rb + 3*8 + p3]; int ii = mi[rb + 3*8 + p3];
          if (v < bvv || (v == bvv && ii < bii)) { bvv = v; bii = ii; bq = 3; }
        }
        p0 += (bq == 0); p1 += (bq == 1); p2 += (bq == 2); p3 += (bq == 3);
        op[o] = bii;
      }
    }
  }
}

// ---------------------------------------------------------------------------
__global__ __launch_bounds__(256) void gkan_kernel(
    const float* __restrict__ hs, const float* __restrict__ hw,
    const int* __restrict__ nbr, const float* __restrict__ bias,
    const float* __restrict__ kan_a, const float* __restrict__ kan_b,
    float* __restrict__ gpre)
{
  int row = blockIdx.x * 4 + (threadIdx.x >> 6);
  int d = threadIdx.x & 63;
  float degf = 8.0f + 1e-6f;
  float coef = 1.0f / degf;
  size_t bbase = (size_t)(row / 729) * 729;
  float v = hs[(size_t)row * 64 + d] + hw[(size_t)row * 64 + d] + bias[d];
  float nsum = 0.f;
  #pragma unroll
  for (int j = 0; j < 8; ++j) {
    int m = nbr[(size_t)row * 8 + j];
    nsum += hw[(bbase + m) * 64 + d];
  }
  v += coef * nsum;
  float a0 = kan_a[d*3], a1 = kan_a[d*3+1], a2 = kan_a[d*3+2];
  float b0 = kan_b[d*2], b1 = kan_b[d*2+1];
  float v2 = v * v;
  float num = a0 + a1*v + a2*v2;
  float den = 1.f + fabsf(b0*v + b1*v2);
  gpre[(size_t)row * 64 + d] = num / (den + 1e-8f);
}

__global__ __launch_bounds__(256) void stats_tok(
    const float* __restrict__ g, double* __restrict__ stats)
{
  int d = threadIdx.x & 63, qq = threadIdx.x >> 6;
  int r0 = blockIdx.x * 183;
  int rend = r0 + 183; if (rend > NROWS) rend = NROWS;
  float sm = 0.f, sq = 0.f;
  for (int r = r0 + qq; r < rend; r += 4) {
    float v = g[(size_t)r * 64 + d];
    sm += v; sq += v * v;
  }
  __shared__ float ls[256], lq[256];
  ls[threadIdx.x] = sm; lq[threadIdx.x] = sq;
  __syncthreads();
  if (threadIdx.x < 64) {
    sm = ls[d] + ls[64+d] + ls[128+d] + ls[192+d];
    sq = lq[d] + lq[64+d] + lq[128+d] + lq[192+d];
    atomicAdd(&stats[d], (double)sm);
    atomicAdd(&stats[64 + d], (double)sq);
  }
}

// ---------------------------------------------------------------------------
__global__ __launch_bounds__(256) void fuzzy_attn(
    const float* __restrict__ gpre, const float* __restrict__ scshG,
    const float* __restrict__ centers, const float* __restrict__ gam,
    const float* __restrict__ w1, const float* __restrict__ b1,
    const float* __restrict__ w2, const float* __restrict__ b2,
    float* __restrict__ g2)
{
  int wv = threadIdx.x >> 6, d = threadIdx.x & 63;
  int row = blockIdx.x * 4 + wv;
  __shared__ float s_rbf[4][64];
  __shared__ float s_a1[4][16];
  float v = gpre[(size_t)row * 64 + d];
  float gn = fmaf(v, scshG[d], scshG[64 + d]);
  float acc = 0.f;
  #pragma unroll
  for (int f = 0; f < 9; ++f) {
    float dc = gn - centers[d*9 + f];
    acc += expf(-fabsf(gam[d*9 + f]) * dc * dc);
  }
  s_rbf[wv][d] = acc + 9e-10f;
  __syncthreads();
  if (d < 16) {
    float a = b1[d];
    #pragma unroll 8
    for (int k = 0; k < 64; ++k) a += w1[d*64 + k] * s_rbf[wv][k];
    s_a1[wv][d] = fmaxf(a, 0.f);
  }
  __syncthreads();
  float a2 = b2[d];
  #pragma unroll
  for (int i = 0; i < 16; ++i) a2 += w2[d*16 + i] * s_a1[wv][i];
  float sig = 1.f / (1.f + expf(-a2));
  g2[(size_t)row * 64 + d] = gn * (1.f + sig);
}

__global__ __launch_bounds__(256) void pool_kernel(
    const float* __restrict__ g2, const float* __restrict__ scshF, float* __restrict__ p)
{
  int b = blockIdx.x;
  int d = threadIdx.x & 63, qq = threadIdx.x >> 6;
  float sc = scshF[d], sh = scshF[64 + d];
  float sm = 0.f, mx = -3.0e38f;
  for (int n = qq; n < 729; n += 4) {
    float v = fmaf(g2[((size_t)b * 729 + n) * 64 + d], sc, sh);
    sm += v; mx = fmaxf(mx, v);
  }
  __shared__ float ls[256], lm[256];
  ls[threadIdx.x] = sm; lm[threadIdx.x] = mx;
  __syncthreads();
  if (threadIdx.x < 64) {
    sm = ls[d] + ls[64+d] + ls[128+d] + ls[192+d];
    mx = fmaxf(fmaxf(lm[d], lm[64+d]), fmaxf(lm[128+d], lm[192+d]));
    p[b * 64 + d] = 0.5f * (sm / 729.f) + 0.5f * mx;
  }
}

__global__ __launch_bounds__(256) void classifier(
    const float* __restrict__ p, const float* __restrict__ f1w, const float* __restrict__ f1b,
    const float* __restrict__ bng, const float* __restrict__ bnb,
    const float* __restrict__ f2w, const float* __restrict__ f2b, float* __restrict__ outp)
{
  __shared__ float s_p[64 * 64];
  __shared__ float s_c[64 * 128];
  __shared__ float s_sc[128], s_sh[128];
  for (int i = threadIdx.x; i < 4096; i += 256) s_p[i] = p[i];
  __syncthreads();
  for (int o = threadIdx.x; o < 8192; o += 256) {
    int b = o >> 7, h = o & 127;
    float acc = f1b[h];
    #pragma unroll 8
    for (int d = 0; d < 64; ++d) acc += s_p[b*64 + d] * f1w[h*64 + d];
    s_c[o] = acc;
  }
  __syncthreads();
  if (threadIdx.x < 128) {
    int h = threadIdx.x;
    float sm = 0.f, sq = 0.f;
    for (int b = 0; b < 64; ++b) { float v = s_c[b*128 + h]; sm += v; sq += v*v; }
    float mu = sm / 64.f;
    float var = sq / 64.f - mu * mu;
    float rstd = rsqrtf(var + 1e-5f);
    float sc = bng[h] * rstd;
    s_sc[h] = sc; s_sh[h] = bnb[h] - mu * sc;
  }
  __syncthreads();
  for (int o = threadIdx.x; o < 1024; o += 256) {
    int b = o >> 4, j = o & 15;
    float acc = f2b[j];
    #pragma unroll 8
    for (int h = 0; h < 128; ++h) {
      float v = fmaxf(fmaf(s_c[b*128 + h], s_sc[h], s_sh[h]), 0.f);
      acc += f2w[j*128 + h] * v;
    }
    outp[o] = acc;
  }
}

// ---------------------------------------------------------------------------
extern "C" void kernel_launch(void* const* d_in, const int* in_sizes, int n_in,
                              void* d_out, int out_size, void* d_ws, size_t ws_size,
                              hipStream_t stream)
{
  const float* x      = (const float*)d_in[0];
  const float* c1w    = (const float*)d_in[1];
  const float* c1b    = (const float*)d_in[2];
  const float* bn1g   = (const float*)d_in[3];
  const float* bn1b   = (const float*)d_in[4];
  const float* c2wt   = (const float*)d_in[5];
  const float* c2b    = (const float*)d_in[6];
  const float* bn2g   = (const float*)d_in[7];
  const float* bn2b   = (const float*)d_in[8];
  const float* c3wt   = (const float*)d_in[9];
  const float* c3b    = (const float*)d_in[10];
  const float* bn3g   = (const float*)d_in[11];
  const float* bn3b   = (const float*)d_in[12];
  const float* wself  = (const float*)d_in[13];
  const float* wnb    = (const float*)d_in[14];
  const float* gbias  = (const float*)d_in[15];
  const float* kana   = (const float*)d_in[16];
  const float* kanb   = (const float*)d_in[17];
  const float* gbng   = (const float*)d_in[18];
  const float* gbnb   = (const float*)d_in[19];
  const float* cent   = (const float*)d_in[20];
  const float* gamr   = (const float*)d_in[21];
  const float* aw1    = (const float*)d_in[22];
  const float* ab1    = (const float*)d_in[23];
  const float* aw2    = (const float*)d_in[24];
  const float* ab2    = (const float*)d_in[25];
  const float* fbng   = (const float*)d_in[26];
  const float* fbnb   = (const float*)d_in[27];
  const float* f1w    = (const float*)d_in[28];
  const float* f1b    = (const float*)d_in[29];
  const float* cbng   = (const float*)d_in[30];
  const float* cbnb   = (const float*)d_in[31];
  const float* f2w    = (const float*)d_in[32];
  const float* f2b    = (const float*)d_in[33];

  char* ws = (char*)d_ws;
  // P holds up to 4 partial slabs (conv1: 4 x 5.97MB; conv2/3: 2 x 11.94MB)
  float*  P     = (float*) (ws + 0);          // 23,887,872 B
  float*  c1    = (float*) (ws + 23887872);   //  5,971,968 B
  float*  c2    = (float*) (ws + 29859840);   // 11,943,936 B
  float*  c3    = (float*) (ws + 41803776);   // 11,943,936 B
  int*    nbr   = (int*)   (ws + 53747712);   //  1,492,992 B
  float*  xx    = (float*) (ws + 55240704);   //    186,624 B
  double* stats = (double*)(ws + 55427328);   //      4,608 B (576 doubles)
  float*  scsh  = (float*) (ws + 55431936);   //      2,304 B (576 floats)
  float*  pbuf  = (float*) (ws + 55434240);   //     16,384 B
  // aliases (disjoint lifetimes on the serialized stream):
  float* hw   = P;                            // after conv reduces consumed P
  float* t    = (float*)(ws + 11943936);      // inside P, after P dead
  float* hs   = c2;                           // after conv3 consumed c2
  float* gpre = c3;                           // after transpose consumed c3
  float* g2   = t;                            // after gemm+dist consumed t

  hipMemsetAsync(stats, 0, 576 * sizeof(double), stream);

  const float inv = 1.0f / 46656.0f;

  // conv1: Cin=200 -> 4 slabs x 50, TC=8 -> 4 groups; grid 64*4*4 = 1024
  conv3x3_v3<8,8,false><<<dim3(1024), dim3(256), 0, stream>>>(
      x,  c1w, nullptr, P, 200, 32, 50, 4);
  conv_reduce_stats<<<dim3(2048), dim3(256), 0, stream>>>(P, c1b, c1, stats, 32, 4);
  bn_finalize<<<dim3(1), dim3(32), 0, stream>>>(stats, bn1g, bn1b, scsh, 32, inv);
  // conv2: Cin=32 -> 2 slabs x 16, 8 groups; grid 1024; BN(conv1) fused on input
  conv3x3_v3<8,8,true><<<dim3(1024), dim3(256), 0, stream>>>(
      c1, c2wt, scsh, P, 32, 64, 16, 2);
  conv_reduce_stats<<<dim3(4096), dim3(256), 0, stream>>>(P, c2b, c2, stats + 64, 64, 2);
  bn_finalize<<<dim3(1), dim3(64), 0, stream>>>(stats + 64, bn2g, bn2b, scsh + 64, 64, inv);
  // conv3: Cin=64 -> 2 slabs x 32, 8 groups; grid 1024; BN(conv2) fused on input
  conv3x3_v3<8,8,true><<<dim3(1024), dim3(256), 0, stream>>>(
      c2, c3wt, scsh + 64, P, 64, 64, 32, 2);
  conv_reduce_stats<<<dim3(4096), dim3(256), 0, stream>>>(P, c3b, c3, stats + 192, 64, 2);
  bn_finalize<<<dim3(1), dim3(64), 0, stream>>>(stats + 192, bn3g, bn3b, scsh + 192, 64, inv);
  // tokens
  bn_transpose_xx<<<dim3(768), dim3(256), 0, stream>>>(c3, scsh + 192, t, xx);
  gemm_selfnb<<<dim3(768), dim3(256), 0, stream>>>(t, wself, wnb, hs, hw);
  dist_topk<<<dim3(768), dim3(256), 0, stream>>>(t, xx, nbr);
  gkan_kernel<<<dim3(11664), dim3(256), 0, stream>>>(hs, hw, nbr, gbias, kana, kanb, gpre);
  stats_tok<<<dim3(256), dim3(256), 0, stream>>>(gpre, stats + 320);
  bn_finalize<<<dim3(1), dim3(64), 0, stream>>>(stats + 320, gbng, gbnb, scsh + 320, 64, inv);
  fuzzy_attn<<<dim3(11664), dim3(256), 0, stream>>>(gpre, scsh + 320, cent, gamr, aw1, ab1, aw2, ab2, g2);
  stats_tok<<<dim3(256), dim3(256), 0, stream>>>(g2, stats + 448);
  bn_finalize<<<dim3(1), dim3(64), 0, stream>>>(stats + 448, fbng, fbnb, scsh + 448, 64, inv);
  pool_kernel<<<dim3(64), dim3(256), 0, stream>>>(g2, scsh + 448, pbuf);
  classifier<<<dim3(1), dim3(256), 0, stream>>>(pbuf, f1w, f1b, cbng, cbnb, f2w, f2b, (float*)d_out);
}

// Round 5
// 994.445 us; speedup vs baseline: 2.2784x; 1.0715x over previous
//
#include <hip/hip_runtime.h>
#include <math.h>

#define BATCH 64
#define NTOK  729
#define DIM   64
#define NROWS 46656   // BATCH*NTOK

// ---------------------------------------------------------------------------
// Direct 3x3 SAME conv, NCHW, 27x27 spatial. (R3-proven, untouched)
// ---------------------------------------------------------------------------
#define SROW 33
#define SCH  (29 * SROW)   // 957 floats per staged channel

template<int CIN_CHUNK, int TC, bool BN_IN>
__global__ __launch_bounds__(256) void conv3x3_v3(
    const float* __restrict__ in, const float* __restrict__ wgt,
    const float* __restrict__ scsh, float* __restrict__ outp,
    int Cin, int Cout, int cinPerSlab, int nslab)
{
  int groups = Cout / TC;
  int blocksPerB = groups * nslab;
  int b = blockIdx.x / blocksPerB;
  int rr = blockIdx.x % blocksPerB;
  int g = rr / nslab;
  int slab = rr % nslab;
  int c_begin = slab * cinPerSlab;
  int c_end = c_begin + cinPerSlab; if (c_end > Cin) c_end = Cin;

  __shared__ float s_in[CIN_CHUNK * SCH];
  __shared__ float s_w[TC * CIN_CHUNK * 12];   // stride 12 -> 16B aligned
  __shared__ float s_sc[CIN_CHUNK];
  __shared__ float s_sh[CIN_CHUNK];

  const int tid = threadIdx.x;
  const bool active = tid < 243;
  const int py = tid / 9;
  const int px3 = (tid % 9) * 3;

  float acc[TC][3];
  #pragma unroll
  for (int t = 0; t < TC; ++t) { acc[t][0]=0.f; acc[t][1]=0.f; acc[t][2]=0.f; }

  const size_t inB = (size_t)b * Cin;

  for (int c0 = c_begin; c0 < c_end; c0 += CIN_CHUNK) {
    int ccn = c_end - c0; if (ccn > CIN_CHUNK) ccn = CIN_CHUNK;
    if (BN_IN && tid < ccn) {
      s_sc[tid] = scsh[c0 + tid];
      s_sh[tid] = scsh[Cin + c0 + tid];
    }
    __syncthreads();   // protects s_in/s_w from previous iteration's readers
    for (int i = tid; i < CIN_CHUNK * SCH; i += 256) {
      int cc = i / SCH; int r2 = i - cc * SCH; int y = r2 / SROW; int x2 = r2 - y * SROW;
      float v = 0.f;
      if (cc < ccn && y >= 1 && y <= 27 && x2 >= 1 && x2 <= 27) {
        v = in[(inB + (c0 + cc)) * 729 + (y - 1) * 27 + (x2 - 1)];
        if (BN_IN) v = fmaxf(fmaf(v, s_sc[cc], s_sh[cc]), 0.f);
      }
      s_in[i] = v;
    }
    for (int i = tid; i < TC * CIN_CHUNK * 9; i += 256) {
      int t = i / (CIN_CHUNK * 9); int r2 = i - t * CIN_CHUNK * 9;
      int cc = r2 / 9; int k = r2 - cc * 9;
      float wv = 0.f;
      if (cc < ccn) wv = wgt[((size_t)(g * TC + t) * Cin + (c0 + cc)) * 9 + k];
      s_w[(t * CIN_CHUNK + cc) * 12 + k] = wv;
    }
    __syncthreads();
    if (active) {
      #pragma unroll 1
      for (int cc = 0; cc < ccn; ++cc) {
        const float* bp = &s_in[cc * SCH + py * SROW + px3];
        float v00=bp[0],        v01=bp[1],        v02=bp[2],        v03=bp[3],        v04=bp[4];
        float v10=bp[SROW],     v11=bp[SROW+1],   v12=bp[SROW+2],   v13=bp[SROW+3],   v14=bp[SROW+4];
        float v20=bp[2*SROW],   v21=bp[2*SROW+1], v22=bp[2*SROW+2], v23=bp[2*SROW+3], v24=bp[2*SROW+4];
        #pragma unroll
        for (int t = 0; t < TC; ++t) {
          const float4 wa = *(const float4*)&s_w[(t * CIN_CHUNK + cc) * 12];
          const float4 wb = *(const float4*)&s_w[(t * CIN_CHUNK + cc) * 12 + 4];
          const float  w8 = s_w[(t * CIN_CHUNK + cc) * 12 + 8];
          acc[t][0] += wa.x*v00+wa.y*v01+wa.z*v02 + wa.w*v10+wb.x*v11+wb.y*v12 + wb.z*v20+wb.w*v21+w8*v22;
          acc[t][1] += wa.x*v01+wa.y*v02+wa.z*v03 + wa.w*v11+wb.x*v12+wb.y*v13 + wb.z*v21+wb.w*v22+w8*v23;
          acc[t][2] += wa.x*v02+wa.y*v03+wa.z*v04 + wa.w*v12+wb.x*v13+wb.y*v14 + wb.z*v22+wb.w*v23+w8*v24;
        }
      }
    }
  }
  if (active) {
    #pragma unroll
    for (int t = 0; t < TC; ++t) {
      size_t base = (((size_t)slab * BATCH + b) * Cout + (g * TC + t)) * 729 + py * 27 + px3;
      outp[base+0]=acc[t][0]; outp[base+1]=acc[t][1]; outp[base+2]=acc[t][2];
    }
  }
}

// ---------------------------------------------------------------------------
__global__ __launch_bounds__(256) void conv_reduce_stats(
    const float* __restrict__ part, const float* __restrict__ bias,
    float* __restrict__ outp, double* __restrict__ stats, int C, int nslab)
{
  int b = blockIdx.x / C;
  int c = blockIdx.x % C;
  size_t slabStride = (size_t)BATCH * C * 729;
  size_t base = ((size_t)b * C + c) * 729;
  float bv = bias[c];
  float bsum = 0.f, bsq = 0.f;
  for (int e = threadIdx.x; e < 729; e += 256) {
    float v = bv;
    for (int s = 0; s < nslab; ++s) v += part[s*slabStride + base + e];
    outp[base + e] = v;
    bsum += v; bsq += v*v;
  }
  #pragma unroll
  for (int off = 32; off > 0; off >>= 1) {
    bsum += __shfl_down(bsum, off);
    bsq  += __shfl_down(bsq, off);
  }
  __shared__ float rs[4], rq[4];
  int wid = threadIdx.x >> 6;
  if ((threadIdx.x & 63) == 0) { rs[wid] = bsum; rq[wid] = bsq; }
  __syncthreads();
  if (threadIdx.x == 0) {
    float s1 = rs[0]+rs[1]+rs[2]+rs[3];
    float q1 = rq[0]+rq[1]+rq[2]+rq[3];
    atomicAdd(&stats[c], (double)s1);
    atomicAdd(&stats[C + c], (double)q1);
  }
}

__global__ void bn_finalize(const double* __restrict__ stats,
                            const float* __restrict__ gamma, const float* __restrict__ beta,
                            float* __restrict__ scsh, int C, float invCount)
{
  int c = threadIdx.x + blockIdx.x * blockDim.x; if (c >= C) return;
  double mu = stats[c] * (double)invCount;
  double var = stats[C + c] * (double)invCount - mu * mu;
  float rstd = (float)(1.0 / sqrt(var + 1e-5));
  float sc = gamma[c] * rstd;
  scsh[c] = sc;
  scsh[C + c] = beta[c] - (float)mu * sc;
}

// ---------------------------------------------------------------------------
// BN+ReLU conv3 output and transpose [B,64,729] -> t [B,729,64]; also xx[b,n].
// XCD-swizzled so t[b] is produced on the same XCD that will consume it.
// ---------------------------------------------------------------------------
__global__ __launch_bounds__(256) void bn_transpose_xx(
    const float* __restrict__ c3, const float* __restrict__ scsh,
    float* __restrict__ t, float* __restrict__ xx)
{
  int lb = (blockIdx.x & 7) * 96 + (blockIdx.x >> 3);   // 768 % 8 == 0, bijective
  int b = lb / 12, nt = lb % 12, n0 = nt * 64;
  __shared__ float s[64 * 65];
  for (int i = threadIdx.x; i < 4096; i += 256) {
    int d = i >> 6, j = i & 63; int n = n0 + j;
    float v = 0.f;
    if (n < 729) {
      v = c3[((size_t)b * 64 + d) * 729 + n];
      v = fmaxf(fmaf(v, scsh[d], scsh[64 + d]), 0.f);
    }
    s[d * 65 + j] = v;
  }
  __syncthreads();
  for (int i = threadIdx.x; i < 4096; i += 256) {
    int j = i >> 6, d = i & 63; int n = n0 + j;
    if (n < 729) t[((size_t)b * 729 + n) * 64 + d] = s[d * 65 + j];
  }
  if (threadIdx.x < 64) {
    int j = threadIdx.x; int n = n0 + j;
    if (n < 729) {
      float sm = 0.f;
      #pragma unroll
      for (int d = 0; d < 64; ++d) { float v = s[d * 65 + j]; sm += v * v; }
      xx[b * 729 + n] = sm;
    }
  }
}

// ---------------------------------------------------------------------------
// hs = t @ w_self, hw = t @ w_nb. v2: transposed t staging + b128 frag loads,
// weights staged [d][j] stride 68 (naturally d-major), float4 stores.
// ---------------------------------------------------------------------------
__global__ __launch_bounds__(256) void gemm_selfnb(
    const float* __restrict__ t, const float* __restrict__ wself,
    const float* __restrict__ wnb, float* __restrict__ hs, float* __restrict__ hw)
{
  int lb = (blockIdx.x & 7) * 96 + (blockIdx.x >> 3);
  int b = lb / 12, nt = lb % 12, n0 = nt * 64;
  __shared__ __align__(16) float s_tT[64 * 68];
  __shared__ __align__(16) float s_a[64 * 68];
  __shared__ __align__(16) float s_b[64 * 68];
  const int tid = threadIdx.x;
  // stage t transposed: s_tT[d][n]
  for (int i = tid; i < 1024; i += 256) {
    int n = i >> 4, dq = i & 15;
    float4 v = make_float4(0.f, 0.f, 0.f, 0.f);
    if (n0 + n < 729) v = *(const float4*)&t[((size_t)b * 729 + n0 + n) * 64 + 4 * dq];
    s_tT[(4*dq+0)*68 + n] = v.x;
    s_tT[(4*dq+1)*68 + n] = v.y;
    s_tT[(4*dq+2)*68 + n] = v.z;
    s_tT[(4*dq+3)*68 + n] = v.w;
  }
  // stage weights [d][j] (already d-major)
  for (int i = tid; i < 1024; i += 256) {
    int d = i >> 4, jq = i & 15;
    *(float4*)&s_a[d*68 + 4*jq] = *(const float4*)&wself[d*64 + 4*jq];
    *(float4*)&s_b[d*68 + 4*jq] = *(const float4*)&wnb[d*64 + 4*jq];
  }
  __syncthreads();
  int ty = tid >> 4, tx = tid & 15;
  float acc0[4][4], acc1[4][4];
  #pragma unroll
  for (int i = 0; i < 4; ++i)
    #pragma unroll
    for (int j = 0; j < 4; ++j) { acc0[i][j] = 0.f; acc1[i][j] = 0.f; }
  #pragma unroll 8
  for (int d = 0; d < 64; ++d) {
    float4 av = *(const float4*)&s_tT[d*68 + 4*ty];
    float4 b1 = *(const float4*)&s_a[d*68 + 4*tx];
    float4 b2 = *(const float4*)&s_b[d*68 + 4*tx];
    float a[4] = {av.x, av.y, av.z, av.w};
    float u[4] = {b1.x, b1.y, b1.z, b1.w};
    float w[4] = {b2.x, b2.y, b2.z, b2.w};
    #pragma unroll
    for (int i = 0; i < 4; ++i)
      #pragma unroll
      for (int j = 0; j < 4; ++j) { acc0[i][j] += a[i]*u[j]; acc1[i][j] += a[i]*w[j]; }
  }
  #pragma unroll
  for (int i = 0; i < 4; ++i) {
    int n = n0 + 4*ty + i;
    if (n < 729) {
      size_t o = ((size_t)b * 729 + n) * 64 + 4*tx;
      *(float4*)&hs[o] = make_float4(acc0[i][0], acc0[i][1], acc0[i][2], acc0[i][3]);
      *(float4*)&hw[o] = make_float4(acc1[i][0], acc1[i][1], acc1[i][2], acc1[i][3]);
    }
  }
}

// ---------------------------------------------------------------------------
// kNN v2: transposed staging (b128 frag loads), 2 barriers/tile (scan of tile
// k overlapped with staging of tile k+1), float4 score write/scan, XCD swizzle.
// Ranking: (xx[m] - 2*dot, idx) lexicographic == stable top_k of clamped dist.
// ---------------------------------------------------------------------------
__global__ __launch_bounds__(256) void dist_topk(
    const float* __restrict__ t, const float* __restrict__ xx, int* __restrict__ nbr)
{
  int lb = (blockIdx.x & 7) * 96 + (blockIdx.x >> 3);
  int b = lb / 12, nt = lb % 12, n0 = nt * 64;
  __shared__ __align__(16) float s_nT[64 * 68];
  __shared__ __align__(16) float s_mT[64 * 68];
  __shared__ __align__(16) float s_S[64 * 68];

  const int tid = threadIdx.x;
  const int ty = tid >> 4, tx = tid & 15;
  const int r = tid & 63, q = tid >> 6;
  const int n_self = n0 + r;
  const size_t tb = (size_t)b * 729;

  float kv[8]; int ki[8];
  #pragma unroll
  for (int i = 0; i < 8; ++i) { kv[i] = 3.0e38f; ki[i] = 0x7fffffff; }

  // stage n-tile transposed
  for (int i = tid; i < 1024; i += 256) {
    int n = i >> 4, dq = i & 15;
    float4 v = make_float4(0.f, 0.f, 0.f, 0.f);
    if (n0 + n < 729) v = *(const float4*)&t[(tb + n0 + n) * 64 + 4 * dq];
    s_nT[(4*dq+0)*68 + n] = v.x;
    s_nT[(4*dq+1)*68 + n] = v.y;
    s_nT[(4*dq+2)*68 + n] = v.z;
    s_nT[(4*dq+3)*68 + n] = v.w;
  }
  // stage m-tile 0 transposed
  for (int i = tid; i < 1024; i += 256) {
    int m = i >> 4, dq = i & 15;
    float4 v = *(const float4*)&t[(tb + m) * 64 + 4 * dq];   // tile 0 fully valid
    s_mT[(4*dq+0)*68 + m] = v.x;
    s_mT[(4*dq+1)*68 + m] = v.y;
    s_mT[(4*dq+2)*68 + m] = v.z;
    s_mT[(4*dq+3)*68 + m] = v.w;
  }
  __syncthreads();

  for (int mt = 0; mt < 12; ++mt) {
    int m0 = mt * 64;
    // GEMM 64x64x64: 2x ds_read_b128 + 16 FMA per d
    float acc[4][4];
    #pragma unroll
    for (int i = 0; i < 4; ++i)
      #pragma unroll
      for (int j = 0; j < 4; ++j) acc[i][j] = 0.f;
    #pragma unroll 8
    for (int d = 0; d < 64; ++d) {
      float4 av4 = *(const float4*)&s_nT[d*68 + 4*ty];
      float4 bv4 = *(const float4*)&s_mT[d*68 + 4*tx];
      float a[4] = {av4.x, av4.y, av4.z, av4.w};
      float bb[4] = {bv4.x, bv4.y, bv4.z, bv4.w};
      #pragma unroll
      for (int i = 0; i < 4; ++i)
        #pragma unroll
        for (int j = 0; j < 4; ++j) acc[i][j] += a[i] * bb[j];
    }
    // score write (float4 rows)
    float xm[4];
    #pragma unroll
    for (int j = 0; j < 4; ++j) {
      int m = m0 + 4*tx + j;
      xm[j] = (m < 729) ? xx[b * 729 + m] : 3.0e38f;
    }
    #pragma unroll
    for (int i = 0; i < 4; ++i) {
      float4 sc = make_float4(fmaf(-2.f, acc[i][0], xm[0]), fmaf(-2.f, acc[i][1], xm[1]),
                              fmaf(-2.f, acc[i][2], xm[2]), fmaf(-2.f, acc[i][3], xm[3]));
      *(float4*)&s_S[(4*ty + i)*68 + 4*tx] = sc;
    }
    __syncthreads();
    // stage next m-tile (s_mT free: GEMM done) while scanning s_S
    if (mt < 11) {
      int m0n = (mt + 1) * 64;
      for (int i = tid; i < 1024; i += 256) {
        int m = i >> 4, dq = i & 15;
        float4 v = make_float4(0.f, 0.f, 0.f, 0.f);
        if (m0n + m < 729) v = *(const float4*)&t[(tb + m0n + m) * 64 + 4 * dq];
        s_mT[(4*dq+0)*68 + m] = v.x;
        s_mT[(4*dq+1)*68 + m] = v.y;
        s_mT[(4*dq+2)*68 + m] = v.z;
        s_mT[(4*dq+3)*68 + m] = v.w;
      }
    }
    // scan: thread (r,q) handles cols q*16..q*16+15 of row r
    #pragma unroll
    for (int c = 0; c < 4; ++c) {
      float4 s4 = *(const float4*)&s_S[r*68 + q*16 + 4*c];
      float sv[4] = {s4.x, s4.y, s4.z, s4.w};
      #pragma unroll
      for (int k = 0; k < 4; ++k) {
        int m = m0 + q*16 + 4*c + k;
        bool valid = (m < 729) && (m != n_self);
        bool lt = valid && ((sv[k] < kv[7]) || (sv[k] == kv[7] && m < ki[7]));
        if (lt) {
          float cv = sv[k]; int ci = m;
          #pragma unroll
          for (int ii = 0; ii < 8; ++ii) {
            bool less = (cv < kv[ii]) || (cv == kv[ii] && ci < ki[ii]);
            float tv = less ? kv[ii] : cv; int ti = less ? ki[ii] : ci;
            kv[ii] = less ? cv : kv[ii]; ki[ii] = less ? ci : ki[ii];
            cv = tv; ci = ti;
          }
        }
      }
    }
    __syncthreads();
  }
  // merge the 4 per-thread lists per row (reuse s_mT/s_nT as val/idx [64][33])
  float* mv = s_mT;
  int*   mi = (int*)s_nT;
  #pragma unroll
  for (int i2 = 0; i2 < 8; ++i2) { mv[r*33 + q*8 + i2] = kv[i2]; mi[r*33 + q*8 + i2] = ki[i2]; }
  __syncthreads();
  if (tid < 64) {
    int n = n0 + tid;
    if (n < 729) {
      int rb = tid * 33;
      int p0 = 0, p1 = 0, p2 = 0, p3 = 0;
      int* op = &nbr[((size_t)b * 729 + n) * 8];
      for (int o = 0; o < 8; ++o) {
        float bvv = 3.5e38f; int bii = 0x7fffffff; int bq = 0;
        {
          float v = mv[rb + 0*8 + p0]; int ii = mi[rb + 0*8 + p0];
          if (v < bvv || (v == bvv && ii < bii)) { bvv = v; bii = ii; bq = 0; }
        }
        {
          float v = mv[rb + 1*8 + p1]; int ii = mi[rb + 1*8 + p1];
          if (v < bvv || (v == bvv && ii < bii)) { bvv = v; bii = ii; bq = 1; }
        }
        {
          float v = mv[rb + 2*8 + p2]; int ii = mi[rb + 2*8 + p2];
          if (v < bvv || (v == bvv && ii < bii)) { bvv = v; bii = ii; bq = 2; }
        }
        {
          float v = mv[rb + 3*8 + p3]; int ii = mi[rb + 3*8 + p3];
          if (v < bvv || (v == bvv && ii < bii)) { bvv = v; bii = ii; bq = 3; }
        }
        p0 += (bq == 0); p1 += (bq == 1); p2 += (bq == 2); p3 += (bq == 3);
        op[o] = bii;
      }
    }
  }
}

// ---------------------------------------------------------------------------
__global__ __launch_bounds__(256) void gkan_kernel(
    const float* __restrict__ hs, const float* __restrict__ hw,
    const int* __restrict__ nbr, const float* __restrict__ bias,
    const float* __restrict__ kan_a, const float* __restrict__ kan_b,
    float* __restrict__ gpre)
{
  int row = blockIdx.x * 4 + (threadIdx.x >> 6);
  int d = threadIdx.x & 63;
  float degf = 8.0f + 1e-6f;
  float coef = 1.0f / degf;
  size_t bbase = (size_t)(row / 729) * 729;
  float v = hs[(size_t)row * 64 + d] + hw[(size_t)row * 64 + d] + bias[d];
  float nsum = 0.f;
  #pragma unroll
  for (int j = 0; j < 8; ++j) {
    int m = nbr[(size_t)row * 8 + j];
    nsum += hw[(bbase + m) * 64 + d];
  }
  v += coef * nsum;
  float a0 = kan_a[d*3], a1 = kan_a[d*3+1], a2 = kan_a[d*3+2];
  float b0 = kan_b[d*2], b1 = kan_b[d*2+1];
  float v2 = v * v;
  float num = a0 + a1*v + a2*v2;
  float den = 1.f + fabsf(b0*v + b1*v2);
  gpre[(size_t)row * 64 + d] = num / (den + 1e-8f);
}

__global__ __launch_bounds__(256) void stats_tok(
    const float* __restrict__ g, double* __restrict__ stats)
{
  int d = threadIdx.x & 63, qq = threadIdx.x >> 6;
  int r0 = blockIdx.x * 183;
  int rend = r0 + 183; if (rend > NROWS) rend = NROWS;
  float sm = 0.f, sq = 0.f;
  for (int r = r0 + qq; r < rend; r += 4) {
    float v = g[(size_t)r * 64 + d];
    sm += v; sq += v * v;
  }
  __shared__ float ls[256], lq[256];
  ls[threadIdx.x] = sm; lq[threadIdx.x] = sq;
  __syncthreads();
  if (threadIdx.x < 64) {
    sm = ls[d] + ls[64+d] + ls[128+d] + ls[192+d];
    sq = lq[d] + lq[64+d] + lq[128+d] + lq[192+d];
    atomicAdd(&stats[d], (double)sm);
    atomicAdd(&stats[64 + d], (double)sq);
  }
}

// ---------------------------------------------------------------------------
__global__ __launch_bounds__(256) void fuzzy_attn(
    const float* __restrict__ gpre, const float* __restrict__ scshG,
    const float* __restrict__ centers, const float* __restrict__ gam,
    const float* __restrict__ w1, const float* __restrict__ b1,
    const float* __restrict__ w2, const float* __restrict__ b2,
    float* __restrict__ g2)
{
  int wv = threadIdx.x >> 6, d = threadIdx.x & 63;
  int row = blockIdx.x * 4 + wv;
  __shared__ float s_rbf[4][64];
  __shared__ float s_a1[4][16];
  float v = gpre[(size_t)row * 64 + d];
  float gn = fmaf(v, scshG[d], scshG[64 + d]);
  float acc = 0.f;
  #pragma unroll
  for (int f = 0; f < 9; ++f) {
    float dc = gn - centers[d*9 + f];
    acc += expf(-fabsf(gam[d*9 + f]) * dc * dc);
  }
  s_rbf[wv][d] = acc + 9e-10f;
  __syncthreads();
  if (d < 16) {
    float a = b1[d];
    #pragma unroll 8
    for (int k = 0; k < 64; ++k) a += w1[d*64 + k] * s_rbf[wv][k];
    s_a1[wv][d] = fmaxf(a, 0.f);
  }
  __syncthreads();
  float a2 = b2[d];
  #pragma unroll
  for (int i = 0; i < 16; ++i) a2 += w2[d*16 + i] * s_a1[wv][i];
  float sig = 1.f / (1.f + expf(-a2));
  g2[(size_t)row * 64 + d] = gn * (1.f + sig);
}

__global__ __launch_bounds__(256) void pool_kernel(
    const float* __restrict__ g2, const float* __restrict__ scshF, float* __restrict__ p)
{
  int b = blockIdx.x;
  int d = threadIdx.x & 63, qq = threadIdx.x >> 6;
  float sc = scshF[d], sh = scshF[64 + d];
  float sm = 0.f, mx = -3.0e38f;
  for (int n = qq; n < 729; n += 4) {
    float v = fmaf(g2[((size_t)b * 729 + n) * 64 + d], sc, sh);
    sm += v; mx = fmaxf(mx, v);
  }
  __shared__ float ls[256], lm[256];
  ls[threadIdx.x] = sm; lm[threadIdx.x] = mx;
  __syncthreads();
  if (threadIdx.x < 64) {
    sm = ls[d] + ls[64+d] + ls[128+d] + ls[192+d];
    mx = fmaxf(fmaxf(lm[d], lm[64+d]), fmaxf(lm[128+d], lm[192+d]));
    p[b * 64 + d] = 0.5f * (sm / 729.f) + 0.5f * mx;
  }
}

__global__ __launch_bounds__(256) void classifier(
    const float* __restrict__ p, const float* __restrict__ f1w, const float* __restrict__ f1b,
    const float* __restrict__ bng, const float* __restrict__ bnb,
    const float* __restrict__ f2w, const float* __restrict__ f2b, float* __restrict__ outp)
{
  __shared__ float s_p[64 * 64];
  __shared__ float s_c[64 * 128];
  __shared__ float s_sc[128], s_sh[128];
  for (int i = threadIdx.x; i < 4096; i += 256) s_p[i] = p[i];
  __syncthreads();
  for (int o = threadIdx.x; o < 8192; o += 256) {
    int b = o >> 7, h = o & 127;
    float acc = f1b[h];
    #pragma unroll 8
    for (int d = 0; d < 64; ++d) acc += s_p[b*64 + d] * f1w[h*64 + d];
    s_c[o] = acc;
  }
  __syncthreads();
  if (threadIdx.x < 128) {
    int h = threadIdx.x;
    float sm = 0.f, sq = 0.f;
    for (int b = 0; b < 64; ++b) { float v = s_c[b*128 + h]; sm += v; sq += v*v; }
    float mu = sm / 64.f;
    float var = sq / 64.f - mu * mu;
    float rstd = rsqrtf(var + 1e-5f);
    float sc = bng[h] * rstd;
    s_sc[h] = sc; s_sh[h] = bnb[h] - mu * sc;
  }
  __syncthreads();
  for (int o = threadIdx.x; o < 1024; o += 256) {
    int b = o >> 4, j = o & 15;
    float acc = f2b[j];
    #pragma unroll 8
    for (int h = 0; h < 128; ++h) {
      float v = fmaxf(fmaf(s_c[b*128 + h], s_sc[h], s_sh[h]), 0.f);
      acc += f2w[j*128 + h] * v;
    }
    outp[o] = acc;
  }
}

// ---------------------------------------------------------------------------
extern "C" void kernel_launch(void* const* d_in, const int* in_sizes, int n_in,
                              void* d_out, int out_size, void* d_ws, size_t ws_size,
                              hipStream_t stream)
{
  const float* x      = (const float*)d_in[0];
  const float* c1w    = (const float*)d_in[1];
  const float* c1b    = (const float*)d_in[2];
  const float* bn1g   = (const float*)d_in[3];
  const float* bn1b   = (const float*)d_in[4];
  const float* c2wt   = (const float*)d_in[5];
  const float* c2b    = (const float*)d_in[6];
  const float* bn2g   = (const float*)d_in[7];
  const float* bn2b   = (const float*)d_in[8];
  const float* c3wt   = (const float*)d_in[9];
  const float* c3b    = (const float*)d_in[10];
  const float* bn3g   = (const float*)d_in[11];
  const float* bn3b   = (const float*)d_in[12];
  const float* wself  = (const float*)d_in[13];
  const float* wnb    = (const float*)d_in[14];
  const float* gbias  = (const float*)d_in[15];
  const float* kana   = (const float*)d_in[16];
  const float* kanb   = (const float*)d_in[17];
  const float* gbng   = (const float*)d_in[18];
  const float* gbnb   = (const float*)d_in[19];
  const float* cent   = (const float*)d_in[20];
  const float* gamr   = (const float*)d_in[21];
  const float* aw1    = (const float*)d_in[22];
  const float* ab1    = (const float*)d_in[23];
  const float* aw2    = (const float*)d_in[24];
  const float* ab2    = (const float*)d_in[25];
  const float* fbng   = (const float*)d_in[26];
  const float* fbnb   = (const float*)d_in[27];
  const float* f1w    = (const float*)d_in[28];
  const float* f1b    = (const float*)d_in[29];
  const float* cbng   = (const float*)d_in[30];
  const float* cbnb   = (const float*)d_in[31];
  const float* f2w    = (const float*)d_in[32];
  const float* f2b    = (const float*)d_in[33];

  char* ws = (char*)d_ws;
  float*  P     = (float*) (ws + 0);          // 23,887,872 B (partial slabs)
  float*  c1    = (float*) (ws + 23887872);   //  5,971,968 B
  float*  c2    = (float*) (ws + 29859840);   // 11,943,936 B
  float*  c3    = (float*) (ws + 41803776);   // 11,943,936 B
  int*    nbr   = (int*)   (ws + 53747712);   //  1,492,992 B
  float*  xx    = (float*) (ws + 55240704);   //    186,624 B
  double* stats = (double*)(ws + 55427328);   //      4,608 B
  float*  scsh  = (float*) (ws + 55431936);   //      2,304 B
  float*  pbuf  = (float*) (ws + 55434240);   //     16,384 B
  // aliases (disjoint lifetimes on the serialized stream):
  float* hw   = P;
  float* t    = (float*)(ws + 11943936);      // inside P, after P dead
  float* hs   = c2;
  float* gpre = c3;
  float* g2   = t;

  hipMemsetAsync(stats, 0, 576 * sizeof(double), stream);

  const float inv = 1.0f / 46656.0f;

  conv3x3_v3<8,8,false><<<dim3(1024), dim3(256), 0, stream>>>(
      x,  c1w, nullptr, P, 200, 32, 50, 4);
  conv_reduce_stats<<<dim3(2048), dim3(256), 0, stream>>>(P, c1b, c1, stats, 32, 4);
  bn_finalize<<<dim3(1), dim3(32), 0, stream>>>(stats, bn1g, bn1b, scsh, 32, inv);
  conv3x3_v3<8,8,true><<<dim3(1024), dim3(256), 0, stream>>>(
      c1, c2wt, scsh, P, 32, 64, 16, 2);
  conv_reduce_stats<<<dim3(4096), dim3(256), 0, stream>>>(P, c2b, c2, stats + 64, 64, 2);
  bn_finalize<<<dim3(1), dim3(64), 0, stream>>>(stats + 64, bn2g, bn2b, scsh + 64, 64, inv);
  conv3x3_v3<8,8,true><<<dim3(1024), dim3(256), 0, stream>>>(
      c2, c3wt, scsh + 64, P, 64, 64, 32, 2);
  conv_reduce_stats<<<dim3(4096), dim3(256), 0, stream>>>(P, c3b, c3, stats + 192, 64, 2);
  bn_finalize<<<dim3(1), dim3(64), 0, stream>>>(stats + 192, bn3g, bn3b, scsh + 192, 64, inv);
  // tokens
  bn_transpose_xx<<<dim3(768), dim3(256), 0, stream>>>(c3, scsh + 192, t, xx);
  gemm_selfnb<<<dim3(768), dim3(256), 0, stream>>>(t, wself, wnb, hs, hw);
  dist_topk<<<dim3(768), dim3(256), 0, stream>>>(t, xx, nbr);
  gkan_kernel<<<dim3(11664), dim3(256), 0, stream>>>(hs, hw, nbr, gbias, kana, kanb, gpre);
  stats_tok<<<dim3(256), dim3(256), 0, stream>>>(gpre, stats + 320);
  bn_finalize<<<dim3(1), dim3(64), 0, stream>>>(stats + 320, gbng, gbnb, scsh + 320, 64, inv);
  fuzzy_attn<<<dim3(11664), dim3(256), 0, stream>>>(gpre, scsh + 320, cent, gamr, aw1, ab1, aw2, ab2, g2);
  stats_tok<<<dim3(256), dim3(256), 0, stream>>>(g2, stats + 448);
  bn_finalize<<<dim3(1), dim3(64), 0, stream>>>(stats + 448, fbng, fbnb, scsh + 448, 64, inv);
  pool_kernel<<<dim3(64), dim3(256), 0, stream>>>(g2, scsh + 448, pbuf);
  classifier<<<dim3(1), dim3(256), 0, stream>>>(pbuf, f1w, f1b, cbng, cbnb, f2w, f2b, (float*)d_out);
}

// Round 6
// 885.635 us; speedup vs baseline: 2.5583x; 1.1229x over previous
//
#include <hip/hip_runtime.h>
#include <math.h>

#define BATCH 64
#define NTOK  729
#define DIM   64
#define NROWS 46656   // BATCH*NTOK

// ---------------------------------------------------------------------------
// Direct 3x3 SAME conv, NCHW, 27x27 spatial. v4:
// LDS-pipe-bound analysis (R5): per-wave weight re-reads dominate (238 of
// 325 LDS-cyc per cc). Amortize by 2 rows x 3 px per thread (6 px) and
// 16 couts/block as 2 sub-groups of 8 (waves 0-1 / 2-3) sharing staged input.
// -> 1.84x less LDS-pipe time per cout. Summation order per output is
// IDENTICAL to v3 (cc ascending, same slab split) -> bitwise-same results.
// Block: 256 threads; per 128-thread group: idx<126 active
// (13 row-pairs + row-26-with-garbage-row-27) x 9 x-triples.
// Output: partial buffer [slab][B][Cout][729].
// ---------------------------------------------------------------------------
#define SROW 33
#define SCH  (29 * SROW)   // 957 floats per staged channel

template<int CIN_CHUNK, bool BN_IN>
__global__ __launch_bounds__(256) void conv3x3_v4(
    const float* __restrict__ in, const float* __restrict__ wgt,
    const float* __restrict__ scsh, float* __restrict__ outp,
    int Cin, int Cout, int cinPerSlab, int nslab)
{
  int bigGroups = Cout / 16;
  int blocksPerB = bigGroups * nslab;
  int b = blockIdx.x / blocksPerB;
  int rr = blockIdx.x % blocksPerB;
  int bg = rr / nslab;
  int slab = rr % nslab;
  int c_begin = slab * cinPerSlab;
  int c_end = c_begin + cinPerSlab; if (c_end > Cin) c_end = Cin;

  __shared__ float s_in[CIN_CHUNK * SCH + SROW];   // +1 pad row: row-29 reads stay in-bounds
  __shared__ float s_w[16 * CIN_CHUNK * 12];       // stride 12 -> 16B aligned
  __shared__ float s_sc[CIN_CHUNK];
  __shared__ float s_sh[CIN_CHUNK];

  const int tid = threadIdx.x;
  const int grp = tid >> 7;          // 0: couts +0..7, 1: couts +8..15
  const int idx = tid & 127;
  const bool active = idx < 126;
  const int rp = idx / 9;            // 0..13
  const int py = 2 * rp;             // 0,2,...,26
  const int px3 = (idx % 9) * 3;
  const bool row2ok = (py + 1) < 27;

  float acc[8][2][3];
  #pragma unroll
  for (int t = 0; t < 8; ++t)
    #pragma unroll
    for (int rI = 0; rI < 2; ++rI) { acc[t][rI][0]=0.f; acc[t][rI][1]=0.f; acc[t][rI][2]=0.f; }

  const size_t inB = (size_t)b * Cin;

  for (int c0 = c_begin; c0 < c_end; c0 += CIN_CHUNK) {
    int ccn = c_end - c0; if (ccn > CIN_CHUNK) ccn = CIN_CHUNK;
    if (BN_IN && tid < ccn) {
      s_sc[tid] = scsh[c0 + tid];
      s_sh[tid] = scsh[Cin + c0 + tid];
    }
    __syncthreads();   // protects s_in/s_w from previous iteration's readers
    for (int i = tid; i < CIN_CHUNK * SCH; i += 256) {
      int cc = i / SCH; int r2 = i - cc * SCH; int y = r2 / SROW; int x2 = r2 - y * SROW;
      float v = 0.f;
      if (cc < ccn && y >= 1 && y <= 27 && x2 >= 1 && x2 <= 27) {
        v = in[(inB + (c0 + cc)) * 729 + (y - 1) * 27 + (x2 - 1)];
        if (BN_IN) v = fmaxf(fmaf(v, s_sc[cc], s_sh[cc]), 0.f);
      }
      s_in[i] = v;
    }
    for (int i = tid; i < 16 * CIN_CHUNK * 9; i += 256) {
      int t = i / (CIN_CHUNK * 9); int r2 = i - t * CIN_CHUNK * 9;
      int cc = r2 / 9; int k = r2 - cc * 9;
      float wv = 0.f;
      if (cc < ccn) wv = wgt[((size_t)(bg * 16 + t) * Cin + (c0 + cc)) * 9 + k];
      s_w[(t * CIN_CHUNK + cc) * 12 + k] = wv;
    }
    __syncthreads();
    if (active) {
      #pragma unroll 1
      for (int cc = 0; cc < ccn; ++cc) {
        const float* bp = &s_in[cc * SCH + py * SROW + px3];
        float r0[5], r1[5], r2[5], r3[5];
        #pragma unroll
        for (int j = 0; j < 5; ++j) {
          r0[j] = bp[j];
          r1[j] = bp[SROW + j];
          r2[j] = bp[2*SROW + j];
          r3[j] = bp[3*SROW + j];   // for py=26 this is garbage; result discarded
        }
        #pragma unroll
        for (int t = 0; t < 8; ++t) {
          const int wb = ((grp * 8 + t) * CIN_CHUNK + cc) * 12;
          const float4 wa = *(const float4*)&s_w[wb];
          const float4 wc = *(const float4*)&s_w[wb + 4];
          const float  w8 = s_w[wb + 8];
          #pragma unroll
          for (int p = 0; p < 3; ++p) {
            acc[t][0][p] += wa.x*r0[p]+wa.y*r0[p+1]+wa.z*r0[p+2]
                          + wa.w*r1[p]+wc.x*r1[p+1]+wc.y*r1[p+2]
                          + wc.z*r2[p]+wc.w*r2[p+1]+w8*r2[p+2];
            acc[t][1][p] += wa.x*r1[p]+wa.y*r1[p+1]+wa.z*r1[p+2]
                          + wa.w*r2[p]+wc.x*r2[p+1]+wc.y*r2[p+2]
                          + wc.z*r3[p]+wc.w*r3[p+1]+w8*r3[p+2];
          }
        }
      }
    }
  }
  if (active) {
    #pragma unroll
    for (int t = 0; t < 8; ++t) {
      size_t base = (((size_t)slab * BATCH + b) * Cout + (bg * 16 + grp * 8 + t)) * 729 + py * 27 + px3;
      outp[base+0]=acc[t][0][0]; outp[base+1]=acc[t][0][1]; outp[base+2]=acc[t][0][2];
      if (row2ok) {
        outp[base+27]=acc[t][1][0]; outp[base+28]=acc[t][1][1]; outp[base+29]=acc[t][1][2];
      }
    }
  }
}

// ---------------------------------------------------------------------------
__global__ __launch_bounds__(256) void conv_reduce_stats(
    const float* __restrict__ part, const float* __restrict__ bias,
    float* __restrict__ outp, double* __restrict__ stats, int C, int nslab)
{
  int b = blockIdx.x / C;
  int c = blockIdx.x % C;
  size_t slabStride = (size_t)BATCH * C * 729;
  size_t base = ((size_t)b * C + c) * 729;
  float bv = bias[c];
  float bsum = 0.f, bsq = 0.f;
  for (int e = threadIdx.x; e < 729; e += 256) {
    float v = bv;
    for (int s = 0; s < nslab; ++s) v += part[s*slabStride + base + e];
    outp[base + e] = v;
    bsum += v; bsq += v*v;
  }
  #pragma unroll
  for (int off = 32; off > 0; off >>= 1) {
    bsum += __shfl_down(bsum, off);
    bsq  += __shfl_down(bsq, off);
  }
  __shared__ float rs[4], rq[4];
  int wid = threadIdx.x >> 6;
  if ((threadIdx.x & 63) == 0) { rs[wid] = bsum; rq[wid] = bsq; }
  __syncthreads();
  if (threadIdx.x == 0) {
    float s1 = rs[0]+rs[1]+rs[2]+rs[3];
    float q1 = rq[0]+rq[1]+rq[2]+rq[3];
    atomicAdd(&stats[c], (double)s1);
    atomicAdd(&stats[C + c], (double)q1);
  }
}

__global__ void bn_finalize(const double* __restrict__ stats,
                            const float* __restrict__ gamma, const float* __restrict__ beta,
                            float* __restrict__ scsh, int C, float invCount)
{
  int c = threadIdx.x + blockIdx.x * blockDim.x; if (c >= C) return;
  double mu = stats[c] * (double)invCount;
  double var = stats[C + c] * (double)invCount - mu * mu;
  float rstd = (float)(1.0 / sqrt(var + 1e-5));
  float sc = gamma[c] * rstd;
  scsh[c] = sc;
  scsh[C + c] = beta[c] - (float)mu * sc;
}

// ---------------------------------------------------------------------------
// BN+ReLU conv3 output and transpose [B,64,729] -> t [B,729,64]; also xx[b,n].
// ---------------------------------------------------------------------------
__global__ __launch_bounds__(256) void bn_transpose_xx(
    const float* __restrict__ c3, const float* __restrict__ scsh,
    float* __restrict__ t, float* __restrict__ xx)
{
  int lb = (blockIdx.x & 7) * 96 + (blockIdx.x >> 3);   // 768 % 8 == 0, bijective
  int b = lb / 12, nt = lb % 12, n0 = nt * 64;
  __shared__ float s[64 * 65];
  for (int i = threadIdx.x; i < 4096; i += 256) {
    int d = i >> 6, j = i & 63; int n = n0 + j;
    float v = 0.f;
    if (n < 729) {
      v = c3[((size_t)b * 64 + d) * 729 + n];
      v = fmaxf(fmaf(v, scsh[d], scsh[64 + d]), 0.f);
    }
    s[d * 65 + j] = v;
  }
  __syncthreads();
  for (int i = threadIdx.x; i < 4096; i += 256) {
    int j = i >> 6, d = i & 63; int n = n0 + j;
    if (n < 729) t[((size_t)b * 729 + n) * 64 + d] = s[d * 65 + j];
  }
  if (threadIdx.x < 64) {
    int j = threadIdx.x; int n = n0 + j;
    if (n < 729) {
      float sm = 0.f;
      #pragma unroll
      for (int d = 0; d < 64; ++d) { float v = s[d * 65 + j]; sm += v * v; }
      xx[b * 729 + n] = sm;
    }
  }
}

// ---------------------------------------------------------------------------
// hs = t @ w_self, hw = t @ w_nb. (R5-proven)
// ---------------------------------------------------------------------------
__global__ __launch_bounds__(256) void gemm_selfnb(
    const float* __restrict__ t, const float* __restrict__ wself,
    const float* __restrict__ wnb, float* __restrict__ hs, float* __restrict__ hw)
{
  int lb = (blockIdx.x & 7) * 96 + (blockIdx.x >> 3);
  int b = lb / 12, nt = lb % 12, n0 = nt * 64;
  __shared__ __align__(16) float s_tT[64 * 68];
  __shared__ __align__(16) float s_a[64 * 68];
  __shared__ __align__(16) float s_b[64 * 68];
  const int tid = threadIdx.x;
  for (int i = tid; i < 1024; i += 256) {
    int n = i >> 4, dq = i & 15;
    float4 v = make_float4(0.f, 0.f, 0.f, 0.f);
    if (n0 + n < 729) v = *(const float4*)&t[((size_t)b * 729 + n0 + n) * 64 + 4 * dq];
    s_tT[(4*dq+0)*68 + n] = v.x;
    s_tT[(4*dq+1)*68 + n] = v.y;
    s_tT[(4*dq+2)*68 + n] = v.z;
    s_tT[(4*dq+3)*68 + n] = v.w;
  }
  for (int i = tid; i < 1024; i += 256) {
    int d = i >> 4, jq = i & 15;
    *(float4*)&s_a[d*68 + 4*jq] = *(const float4*)&wself[d*64 + 4*jq];
    *(float4*)&s_b[d*68 + 4*jq] = *(const float4*)&wnb[d*64 + 4*jq];
  }
  __syncthreads();
  int ty = tid >> 4, tx = tid & 15;
  float acc0[4][4], acc1[4][4];
  #pragma unroll
  for (int i = 0; i < 4; ++i)
    #pragma unroll
    for (int j = 0; j < 4; ++j) { acc0[i][j] = 0.f; acc1[i][j] = 0.f; }
  #pragma unroll 8
  for (int d = 0; d < 64; ++d) {
    float4 av = *(const float4*)&s_tT[d*68 + 4*ty];
    float4 b1 = *(const float4*)&s_a[d*68 + 4*tx];
    float4 b2 = *(const float4*)&s_b[d*68 + 4*tx];
    float a[4] = {av.x, av.y, av.z, av.w};
    float u[4] = {b1.x, b1.y, b1.z, b1.w};
    float w[4] = {b2.x, b2.y, b2.z, b2.w};
    #pragma unroll
    for (int i = 0; i < 4; ++i)
      #pragma unroll
      for (int j = 0; j < 4; ++j) { acc0[i][j] += a[i]*u[j]; acc1[i][j] += a[i]*w[j]; }
  }
  #pragma unroll
  for (int i = 0; i < 4; ++i) {
    int n = n0 + 4*ty + i;
    if (n < 729) {
      size_t o = ((size_t)b * 729 + n) * 64 + 4*tx;
      *(float4*)&hs[o] = make_float4(acc0[i][0], acc0[i][1], acc0[i][2], acc0[i][3]);
      *(float4*)&hw[o] = make_float4(acc1[i][0], acc1[i][1], acc1[i][2], acc1[i][3]);
    }
  }
}

// ---------------------------------------------------------------------------
// kNN v2 (R5-proven). Ranking: (xx[m]-2*dot, idx) lexicographic.
// ---------------------------------------------------------------------------
__global__ __launch_bounds__(256) void dist_topk(
    const float* __restrict__ t, const float* __restrict__ xx, int* __restrict__ nbr)
{
  int lb = (blockIdx.x & 7) * 96 + (blockIdx.x >> 3);
  int b = lb / 12, nt = lb % 12, n0 = nt * 64;
  __shared__ __align__(16) float s_nT[64 * 68];
  __shared__ __align__(16) float s_mT[64 * 68];
  __shared__ __align__(16) float s_S[64 * 68];

  const int tid = threadIdx.x;
  const int ty = tid >> 4, tx = tid & 15;
  const int r = tid & 63, q = tid >> 6;
  const int n_self = n0 + r;
  const size_t tb = (size_t)b * 729;

  float kv[8]; int ki[8];
  #pragma unroll
  for (int i = 0; i < 8; ++i) { kv[i] = 3.0e38f; ki[i] = 0x7fffffff; }

  for (int i = tid; i < 1024; i += 256) {
    int n = i >> 4, dq = i & 15;
    float4 v = make_float4(0.f, 0.f, 0.f, 0.f);
    if (n0 + n < 729) v = *(const float4*)&t[(tb + n0 + n) * 64 + 4 * dq];
    s_nT[(4*dq+0)*68 + n] = v.x;
    s_nT[(4*dq+1)*68 + n] = v.y;
    s_nT[(4*dq+2)*68 + n] = v.z;
    s_nT[(4*dq+3)*68 + n] = v.w;
  }
  for (int i = tid; i < 1024; i += 256) {
    int m = i >> 4, dq = i & 15;
    float4 v = *(const float4*)&t[(tb + m) * 64 + 4 * dq];
    s_mT[(4*dq+0)*68 + m] = v.x;
    s_mT[(4*dq+1)*68 + m] = v.y;
    s_mT[(4*dq+2)*68 + m] = v.z;
    s_mT[(4*dq+3)*68 + m] = v.w;
  }
  __syncthreads();

  for (int mt = 0; mt < 12; ++mt) {
    int m0 = mt * 64;
    float acc[4][4];
    #pragma unroll
    for (int i = 0; i < 4; ++i)
      #pragma unroll
      for (int j = 0; j < 4; ++j) acc[i][j] = 0.f;
    #pragma unroll 8
    for (int d = 0; d < 64; ++d) {
      float4 av4 = *(const float4*)&s_nT[d*68 + 4*ty];
      float4 bv4 = *(const float4*)&s_mT[d*68 + 4*tx];
      float a[4] = {av4.x, av4.y, av4.z, av4.w};
      float bb[4] = {bv4.x, bv4.y, bv4.z, bv4.w};
      #pragma unroll
      for (int i = 0; i < 4; ++i)
        #pragma unroll
        for (int j = 0; j < 4; ++j) acc[i][j] += a[i] * bb[j];
    }
    float xm[4];
    #pragma unroll
    for (int j = 0; j < 4; ++j) {
      int m = m0 + 4*tx + j;
      xm[j] = (m < 729) ? xx[b * 729 + m] : 3.0e38f;
    }
    #pragma unroll
    for (int i = 0; i < 4; ++i) {
      float4 sc = make_float4(fmaf(-2.f, acc[i][0], xm[0]), fmaf(-2.f, acc[i][1], xm[1]),
                              fmaf(-2.f, acc[i][2], xm[2]), fmaf(-2.f, acc[i][3], xm[3]));
      *(float4*)&s_S[(4*ty + i)*68 + 4*tx] = sc;
    }
    __syncthreads();
    if (mt < 11) {
      int m0n = (mt + 1) * 64;
      for (int i = tid; i < 1024; i += 256) {
        int m = i >> 4, dq = i & 15;
        float4 v = make_float4(0.f, 0.f, 0.f, 0.f);
        if (m0n + m < 729) v = *(const float4*)&t[(tb + m0n + m) * 64 + 4 * dq];
        s_mT[(4*dq+0)*68 + m] = v.x;
        s_mT[(4*dq+1)*68 + m] = v.y;
        s_mT[(4*dq+2)*68 + m] = v.z;
        s_mT[(4*dq+3)*68 + m] = v.w;
      }
    }
    #pragma unroll
    for (int c = 0; c < 4; ++c) {
      float4 s4 = *(const float4*)&s_S[r*68 + q*16 + 4*c];
      float sv[4] = {s4.x, s4.y, s4.z, s4.w};
      #pragma unroll
      for (int k = 0; k < 4; ++k) {
        int m = m0 + q*16 + 4*c + k;
        bool valid = (m < 729) && (m != n_self);
        bool lt = valid && ((sv[k] < kv[7]) || (sv[k] == kv[7] && m < ki[7]));
        if (lt) {
          float cv = sv[k]; int ci = m;
          #pragma unroll
          for (int ii = 0; ii < 8; ++ii) {
            bool less = (cv < kv[ii]) || (cv == kv[ii] && ci < ki[ii]);
            float tv = less ? kv[ii] : cv; int ti = less ? ki[ii] : ci;
            kv[ii] = less ? cv : kv[ii]; ki[ii] = less ? ci : ki[ii];
            cv = tv; ci = ti;
          }
        }
      }
    }
    __syncthreads();
  }
  float* mv = s_mT;
  int*   mi = (int*)s_nT;
  #pragma unroll
  for (int i2 = 0; i2 < 8; ++i2) { mv[r*33 + q*8 + i2] = kv[i2]; mi[r*33 + q*8 + i2] = ki[i2]; }
  __syncthreads();
  if (tid < 64) {
    int n = n0 + tid;
    if (n < 729) {
      int rb = tid * 33;
      int p0 = 0, p1 = 0, p2 = 0, p3 = 0;
      int* op = &nbr[((size_t)b * 729 + n) * 8];
      for (int o = 0; o < 8; ++o) {
        float bvv = 3.5e38f; int bii = 0x7fffffff; int bq = 0;
        {
          float v = mv[rb + 0*8 + p0]; int ii = mi[rb + 0*8 + p0];
          if (v < bvv || (v == bvv && ii < bii)) { bvv = v; bii = ii; bq = 0; }
        }
        {
          float v = mv[rb + 1*8 + p1]; int ii = mi[rb + 1*8 + p1];
          if (v < bvv || (v == bvv && ii < bii)) { bvv = v; bii = ii; bq = 1; }
        }
        {
          float v = mv[rb + 2*8 + p2]; int ii = mi[rb + 2*8 + p2];
          if (v < bvv || (v == bvv && ii < bii)) { bvv = v; bii = ii; bq = 2; }
        }
        {
          float v = mv[rb + 3*8 + p3]; int ii = mi[rb + 3*8 + p3];
          if (v < bvv || (v == bvv && ii < bii)) { bvv = v; bii = ii; bq = 3; }
        }
        p0 += (bq == 0); p1 += (bq == 1); p2 += (bq == 2); p3 += (bq == 3);
        op[o] = bii;
      }
    }
  }
}

// ---------------------------------------------------------------------------
__global__ __launch_bounds__(256) void gkan_kernel(
    const float* __restrict__ hs, const float* __restrict__ hw,
    const int* __restrict__ nbr, const float* __restrict__ bias,
    const float* __restrict__ kan_a, const float* __restrict__ kan_b,
    float* __restrict__ gpre)
{
  int row = blockIdx.x * 4 + (threadIdx.x >> 6);
  int d = threadIdx.x & 63;
  float degf = 8.0f + 1e-6f;
  float coef = 1.0f / degf;
  size_t bbase = (size_t)(row / 729) * 729;
  float v = hs[(size_t)row * 64 + d] + hw[(size_t)row * 64 + d] + bias[d];
  float nsum = 0.f;
  #pragma unroll
  for (int j = 0; j < 8; ++j) {
    int m = nbr[(size_t)row * 8 + j];
    nsum += hw[(bbase + m) * 64 + d];
  }
  v += coef * nsum;
  float a0 = kan_a[d*3], a1 = kan_a[d*3+1], a2 = kan_a[d*3+2];
  float b0 = kan_b[d*2], b1 = kan_b[d*2+1];
  float v2 = v * v;
  float num = a0 + a1*v + a2*v2;
  float den = 1.f + fabsf(b0*v + b1*v2);
  gpre[(size_t)row * 64 + d] = num / (den + 1e-8f);
}

__global__ __launch_bounds__(256) void stats_tok(
    const float* __restrict__ g, double* __restrict__ stats)
{
  int d = threadIdx.x & 63, qq = threadIdx.x >> 6;
  int r0 = blockIdx.x * 183;
  int rend = r0 + 183; if (rend > NROWS) rend = NROWS;
  float sm = 0.f, sq = 0.f;
  for (int r = r0 + qq; r < rend; r += 4) {
    float v = g[(size_t)r * 64 + d];
    sm += v; sq += v * v;
  }
  __shared__ float ls[256], lq[256];
  ls[threadIdx.x] = sm; lq[threadIdx.x] = sq;
  __syncthreads();
  if (threadIdx.x < 64) {
    sm = ls[d] + ls[64+d] + ls[128+d] + ls[192+d];
    sq = lq[d] + lq[64+d] + lq[128+d] + lq[192+d];
    atomicAdd(&stats[d], (double)sm);
    atomicAdd(&stats[64 + d], (double)sq);
  }
}

// ---------------------------------------------------------------------------
__global__ __launch_bounds__(256) void fuzzy_attn(
    const float* __restrict__ gpre, const float* __restrict__ scshG,
    const float* __restrict__ centers, const float* __restrict__ gam,
    const float* __restrict__ w1, const float* __restrict__ b1,
    const float* __restrict__ w2, const float* __restrict__ b2,
    float* __restrict__ g2)
{
  int wv = threadIdx.x >> 6, d = threadIdx.x & 63;
  int row = blockIdx.x * 4 + wv;
  __shared__ float s_rbf[4][64];
  __shared__ float s_a1[4][16];
  float v = gpre[(size_t)row * 64 + d];
  float gn = fmaf(v, scshG[d], scshG[64 + d]);
  float acc = 0.f;
  #pragma unroll
  for (int f = 0; f < 9; ++f) {
    float dc = gn - centers[d*9 + f];
    acc += expf(-fabsf(gam[d*9 + f]) * dc * dc);
  }
  s_rbf[wv][d] = acc + 9e-10f;
  __syncthreads();
  if (d < 16) {
    float a = b1[d];
    #pragma unroll 8
    for (int k = 0; k < 64; ++k) a += w1[d*64 + k] * s_rbf[wv][k];
    s_a1[wv][d] = fmaxf(a, 0.f);
  }
  __syncthreads();
  float a2 = b2[d];
  #pragma unroll
  for (int i = 0; i < 16; ++i) a2 += w2[d*16 + i] * s_a1[wv][i];
  float sig = 1.f / (1.f + expf(-a2));
  g2[(size_t)row * 64 + d] = gn * (1.f + sig);
}

__global__ __launch_bounds__(256) void pool_kernel(
    const float* __restrict__ g2, const float* __restrict__ scshF, float* __restrict__ p)
{
  int b = blockIdx.x;
  int d = threadIdx.x & 63, qq = threadIdx.x >> 6;
  float sc = scshF[d], sh = scshF[64 + d];
  float sm = 0.f, mx = -3.0e38f;
  for (int n = qq; n < 729; n += 4) {
    float v = fmaf(g2[((size_t)b * 729 + n) * 64 + d], sc, sh);
    sm += v; mx = fmaxf(mx, v);
  }
  __shared__ float ls[256], lm[256];
  ls[threadIdx.x] = sm; lm[threadIdx.x] = mx;
  __syncthreads();
  if (threadIdx.x < 64) {
    sm = ls[d] + ls[64+d] + ls[128+d] + ls[192+d];
    mx = fmaxf(fmaxf(lm[d], lm[64+d]), fmaxf(lm[128+d], lm[192+d]));
    p[b * 64 + d] = 0.5f * (sm / 729.f) + 0.5f * mx;
  }
}

__global__ __launch_bounds__(256) void classifier(
    const float* __restrict__ p, const float* __restrict__ f1w, const float* __restrict__ f1b,
    const float* __restrict__ bng, const float* __restrict__ bnb,
    const float* __restrict__ f2w, const float* __restrict__ f2b, float* __restrict__ outp)
{
  __shared__ float s_p[64 * 64];
  __shared__ float s_c[64 * 128];
  __shared__ float s_sc[128], s_sh[128];
  for (int i = threadIdx.x; i < 4096; i += 256) s_p[i] = p[i];
  __syncthreads();
  for (int o = threadIdx.x; o < 8192; o += 256) {
    int b = o >> 7, h = o & 127;
    float acc = f1b[h];
    #pragma unroll 8
    for (int d = 0; d < 64; ++d) acc += s_p[b*64 + d] * f1w[h*64 + d];
    s_c[o] = acc;
  }
  __syncthreads();
  if (threadIdx.x < 128) {
    int h = threadIdx.x;
    float sm = 0.f, sq = 0.f;
    for (int b = 0; b < 64; ++b) { float v = s_c[b*128 + h]; sm += v; sq += v*v; }
    float mu = sm / 64.f;
    float var = sq / 64.f - mu * mu;
    float rstd = rsqrtf(var + 1e-5f);
    float sc = bng[h] * rstd;
    s_sc[h] = sc; s_sh[h] = bnb[h] - mu * sc;
  }
  __syncthreads();
  for (int o = threadIdx.x; o < 1024; o += 256) {
    int b = o >> 4, j = o & 15;
    float acc = f2b[j];
    #pragma unroll 8
    for (int h = 0; h < 128; ++h) {
      float v = fmaxf(fmaf(s_c[b*128 + h], s_sc[h], s_sh[h]), 0.f);
      acc += f2w[j*128 + h] * v;
    }
    outp[o] = acc;
  }
}

// ---------------------------------------------------------------------------
extern "C" void kernel_launch(void* const* d_in, const int* in_sizes, int n_in,
                              void* d_out, int out_size, void* d_ws, size_t ws_size,
                              hipStream_t stream)
{
  const float* x      = (const float*)d_in[0];
  const float* c1w    = (const float*)d_in[1];
  const float* c1b    = (const float*)d_in[2];
  const float* bn1g   = (const float*)d_in[3];
  const float* bn1b   = (const float*)d_in[4];
  const float* c2wt   = (const float*)d_in[5];
  const float* c2b    = (const float*)d_in[6];
  const float* bn2g   = (const float*)d_in[7];
  const float* bn2b   = (const float*)d_in[8];
  const float* c3wt   = (const float*)d_in[9];
  const float* c3b    = (const float*)d_in[10];
  const float* bn3g   = (const float*)d_in[11];
  const float* bn3b   = (const float*)d_in[12];
  const float* wself  = (const float*)d_in[13];
  const float* wnb    = (const float*)d_in[14];
  const float* gbias  = (const float*)d_in[15];
  const float* kana   = (const float*)d_in[16];
  const float* kanb   = (const float*)d_in[17];
  const float* gbng   = (const float*)d_in[18];
  const float* gbnb   = (const float*)d_in[19];
  const float* cent   = (const float*)d_in[20];
  const float* gamr   = (const float*)d_in[21];
  const float* aw1    = (const float*)d_in[22];
  const float* ab1    = (const float*)d_in[23];
  const float* aw2    = (const float*)d_in[24];
  const float* ab2    = (const float*)d_in[25];
  const float* fbng   = (const float*)d_in[26];
  const float* fbnb   = (const float*)d_in[27];
  const float* f1w    = (const float*)d_in[28];
  const float* f1b    = (const float*)d_in[29];
  const float* cbng   = (const float*)d_in[30];
  const float* cbnb   = (const float*)d_in[31];
  const float* f2w    = (const float*)d_in[32];
  const float* f2b    = (const float*)d_in[33];

  char* ws = (char*)d_ws;
  float*  P     = (float*) (ws + 0);          // 23,887,872 B (partial slabs)
  float*  c1    = (float*) (ws + 23887872);   //  5,971,968 B
  float*  c2    = (float*) (ws + 29859840);   // 11,943,936 B
  float*  c3    = (float*) (ws + 41803776);   // 11,943,936 B
  int*    nbr   = (int*)   (ws + 53747712);   //  1,492,992 B
  float*  xx    = (float*) (ws + 55240704);   //    186,624 B
  double* stats = (double*)(ws + 55427328);   //      4,608 B
  float*  scsh  = (float*) (ws + 55431936);   //      2,304 B
  float*  pbuf  = (float*) (ws + 55434240);   //     16,384 B
  // aliases (disjoint lifetimes on the serialized stream):
  float* hw   = P;
  float* t    = (float*)(ws + 11943936);      // inside P, after P dead
  float* hs   = c2;
  float* gpre = c3;
  float* g2   = t;

  hipMemsetAsync(stats, 0, 576 * sizeof(double), stream);

  const float inv = 1.0f / 46656.0f;

  // conv1: 2 biggroups x 4 slabs x 64 b = 512 blocks; cc order identical to v3
  conv3x3_v4<8,false><<<dim3(512), dim3(256), 0, stream>>>(
      x,  c1w, nullptr, P, 200, 32, 50, 4);
  conv_reduce_stats<<<dim3(2048), dim3(256), 0, stream>>>(P, c1b, c1, stats, 32, 4);
  bn_finalize<<<dim3(1), dim3(32), 0, stream>>>(stats, bn1g, bn1b, scsh, 32, inv);
  // conv2: 4 biggroups x 2 slabs -> 512 blocks
  conv3x3_v4<8,true><<<dim3(512), dim3(256), 0, stream>>>(
      c1, c2wt, scsh, P, 32, 64, 16, 2);
  conv_reduce_stats<<<dim3(4096), dim3(256), 0, stream>>>(P, c2b, c2, stats + 64, 64, 2);
  bn_finalize<<<dim3(1), dim3(64), 0, stream>>>(stats + 64, bn2g, bn2b, scsh + 64, 64, inv);
  // conv3: 4 biggroups x 2 slabs -> 512 blocks
  conv3x3_v4<8,true><<<dim3(512), dim3(256), 0, stream>>>(
      c2, c3wt, scsh + 64, P, 64, 64, 32, 2);
  conv_reduce_stats<<<dim3(4096), dim3(256), 0, stream>>>(P, c3b, c3, stats + 192, 64, 2);
  bn_finalize<<<dim3(1), dim3(64), 0, stream>>>(stats + 192, bn3g, bn3b, scsh + 192, 64, inv);
  // tokens
  bn_transpose_xx<<<dim3(768), dim3(256), 0, stream>>>(c3, scsh + 192, t, xx);
  gemm_selfnb<<<dim3(768), dim3(256), 0, stream>>>(t, wself, wnb, hs, hw);
  dist_topk<<<dim3(768), dim3(256), 0, stream>>>(t, xx, nbr);
  gkan_kernel<<<dim3(11664), dim3(256), 0, stream>>>(hs, hw, nbr, gbias, kana, kanb, gpre);
  stats_tok<<<dim3(256), dim3(256), 0, stream>>>(gpre, stats + 320);
  bn_finalize<<<dim3(1), dim3(64), 0, stream>>>(stats + 320, gbng, gbnb, scsh + 320, 64, inv);
  fuzzy_attn<<<dim3(11664), dim3(256), 0, stream>>>(gpre, scsh + 320, cent, gamr, aw1, ab1, aw2, ab2, g2);
  stats_tok<<<dim3(256), dim3(256), 0, stream>>>(g2, stats + 448);
  bn_finalize<<<dim3(1), dim3(64), 0, stream>>>(stats + 448, fbng, fbnb, scsh + 448, 64, inv);
  pool_kernel<<<dim3(64), dim3(256), 0, stream>>>(g2, scsh + 448, pbuf);
  classifier<<<dim3(1), dim3(256), 0, stream>>>(pbuf, f1w, f1b, cbng, cbnb, f2w, f2b, (float*)d_out);
}